// Round 1
// baseline (1759.696 us; speedup 1.0000x reference)
//
#include <hip/hip_runtime.h>
#include <math.h>

#define NFFT 512
#define HOP  128
#define PADW 256
#define TLEN 64000
#define NF   501
#define FP   256
#define CH   8
#define BATCH 8
#define HID  512
#define YLEN 64512  // NFFT + HOP*(NF-1)

// ---------------- tables: cos, sin (of 2*pi*j/512), hann window ----------------
__global__ void k_tables(float* tw) {
    int j = threadIdx.x + blockIdx.x * blockDim.x;
    if (j < 512) {
        float ang = (float)(2.0 * M_PI * (double)j / 512.0);
        tw[j]        = cosf(ang);
        tw[512 + j]  = sinf(ang);
        tw[1024 + j] = 0.5f - 0.5f * cosf(ang);
    }
}

// ---------------- STFT: one block per (b,c,frame), thread k computes bin k+1 ----------------
__global__ __launch_bounds__(256) void k_stft(const float* __restrict__ x,
                                              const float* __restrict__ tw,
                                              float2* __restrict__ X,
                                              float* __restrict__ feat) {
    __shared__ float s[512], tc[512], ts[512];
    int blk = blockIdx.x;
    int m = blk % NF;
    int bc = blk / NF;
    int c = bc % CH;
    int b = bc / CH;
    int tid = threadIdx.x;
    for (int t = tid; t < 512; t += 256) {
        tc[t] = tw[t];
        ts[t] = tw[512 + t];
        int j = m * HOP + t - PADW;          // reflect pad
        if (j < 0) j = -j;
        if (j >= TLEN) j = 2 * (TLEN - 1) - j;
        s[t] = x[(size_t)(b * CH + c) * TLEN + j] * tw[1024 + t];
    }
    __syncthreads();
    int k = tid + 1;  // bins 1..256
    float ar = 0.f, ai = 0.f;
    #pragma unroll 8
    for (int t = 0; t < 512; ++t) {
        int id = (k * t) & 511;
        float sv = s[t];
        ar += sv * tc[id];
        ai -= sv * ts[id];
    }
    int f = k - 1;
    X[((size_t)(b * FP + f) * NF + m) * CH + c] = make_float2(ar, ai);
    if (c == 0) feat[((size_t)b * NF + m) * FP + f] = sqrtf(ar * ar + ai * ai);
}

// ---------------- MLP layer 1: h = relu(feat @ w1 + b1) ----------------
__global__ __launch_bounds__(256) void k_mlp1(const float* __restrict__ feat,
                                              const float* __restrict__ w1,
                                              const float* __restrict__ b1,
                                              float* __restrict__ h) {
    __shared__ float fr[8][FP];
    int rb = blockIdx.x >> 1, jc = blockIdx.x & 1;
    int tid = threadIdx.x;
    int row0 = rb * 8;
    for (int i = tid; i < 8 * FP; i += 256)
        fr[i >> 8][i & 255] = feat[(size_t)row0 * FP + i];
    __syncthreads();
    int j = jc * 256 + tid;
    float bj = b1[j];
    float acc[8];
    #pragma unroll
    for (int r = 0; r < 8; ++r) acc[r] = bj;
    for (int f = 0; f < FP; ++f) {
        float wv = w1[(size_t)f * HID + j];
        #pragma unroll
        for (int r = 0; r < 8; ++r) acc[r] += fr[r][f] * wv;
    }
    #pragma unroll
    for (int r = 0; r < 8; ++r)
        h[(size_t)(row0 + r) * HID + j] = fmaxf(acc[r], 0.f);
}

// ---------------- MLP layer 2: m = sigmoid(h @ w2 + b2) ----------------
__global__ __launch_bounds__(256) void k_mlp2(const float* __restrict__ h,
                                              const float* __restrict__ w2,
                                              const float* __restrict__ b2,
                                              float* __restrict__ mo) {
    __shared__ float hr[8][HID];
    int rb = blockIdx.x >> 1, jc = blockIdx.x & 1;
    int tid = threadIdx.x;
    int row0 = rb * 8;
    for (int i = tid; i < 8 * HID; i += 256)
        hr[i >> 9][i & 511] = h[(size_t)row0 * HID + i];
    __syncthreads();
    int j = jc * 256 + tid;
    float bj = b2[j];
    float acc[8];
    #pragma unroll
    for (int r = 0; r < 8; ++r) acc[r] = bj;
    for (int f = 0; f < HID; ++f) {
        float wv = w2[(size_t)f * HID + j];
        #pragma unroll
        for (int r = 0; r < 8; ++r) acc[r] += hr[r][f] * wv;
    }
    #pragma unroll
    for (int r = 0; r < 8; ++r)
        mo[(size_t)(row0 + r) * HID + j] = 1.f / (1.f + expf(-acc[r]));
}

// ---------------- covariance accumulate + 8x8 complex solve, per (b,f) ----------------
__global__ __launch_bounds__(64) void k_cov_solve(const float2* __restrict__ X,
                                                  const float* __restrict__ mo,
                                                  float2* __restrict__ wc) {
    int bf = blockIdx.x;
    int f = bf & 255;
    int b = bf >> 8;
    int lane = threadIdx.x;
    int c = lane >> 3, d = lane & 7;
    float ar = 0.f, ai = 0.f, rr = 0.f, ri = 0.f;
    const float2* Xb = X + (size_t)(b * FP + f) * NF * CH;
    const float* mb = mo + (size_t)b * NF * HID + f;
    for (int n = 0; n < NF; ++n) {
        float2 xc = Xb[n * CH + c];
        float2 xd = Xb[n * CH + d];
        float mt = mb[n * HID];
        float mn = mb[n * HID + FP];
        float pr = xc.x * xd.x + xc.y * xd.y;   // xc * conj(xd)
        float pi = xc.y * xd.x - xc.x * xd.y;
        float w = mt + mn;
        ar += w * pr; ai += w * pi;
        rr += mt * pr; ri += mt * pi;           // valid when d==0
    }
    __shared__ float2 A[8][8];
    __shared__ float2 rhs[8];
    __shared__ float2 sol[8];
    A[c][d] = make_float2(ar, ai);
    if (d == 0) rhs[c] = make_float2(rr, ri);
    __syncthreads();
    if (lane == 0) {
        // Gaussian elimination, no pivot (A is Hermitian positive definite)
        for (int k = 0; k < 8; ++k) {
            float2 p = A[k][k];
            float ip = 1.f / (p.x * p.x + p.y * p.y);
            float invr = p.x * ip, invi = -p.y * ip;
            for (int i = k + 1; i < 8; ++i) {
                float2 aik = A[i][k];
                float fr2 = aik.x * invr - aik.y * invi;
                float fi2 = aik.x * invi + aik.y * invr;
                for (int jj = k; jj < 8; ++jj) {
                    float2 ak = A[k][jj];
                    A[i][jj].x -= fr2 * ak.x - fi2 * ak.y;
                    A[i][jj].y -= fr2 * ak.y + fi2 * ak.x;
                }
                rhs[i].x -= fr2 * rhs[k].x - fi2 * rhs[k].y;
                rhs[i].y -= fr2 * rhs[k].y + fi2 * rhs[k].x;
            }
        }
        for (int k = 7; k >= 0; --k) {
            float sr = rhs[k].x, si = rhs[k].y;
            for (int jj = k + 1; jj < 8; ++jj) {
                float2 ak = A[k][jj];
                float2 xj = sol[jj];
                sr -= ak.x * xj.x - ak.y * xj.y;
                si -= ak.x * xj.y + ak.y * xj.x;
            }
            float2 p = A[k][k];
            float ip = 1.f / (p.x * p.x + p.y * p.y);
            sol[k].x = (sr * p.x + si * p.y) * ip;
            sol[k].y = (si * p.x - sr * p.y) * ip;
        }
        for (int cc = 0; cc < 8; ++cc)   // store conj(bf)
            wc[(size_t)(b * FP + f) * CH + cc] = make_float2(sol[cc].x, -sol[cc].y);
    }
}

// ---------------- beamform: Xe[b][n][f] = sum_c X[b,f,n,c] * wc[b,f,c] ----------------
__global__ __launch_bounds__(256) void k_beamform(const float2* __restrict__ X,
                                                  const float2* __restrict__ wc,
                                                  float2* __restrict__ Xe) {
    int blk = blockIdx.x;
    int n = blk % NF, b = blk / NF;
    int f = threadIdx.x;
    const float2* Xp = X + ((size_t)(b * FP + f) * NF + n) * CH;
    const float2* wp = wc + (size_t)(b * FP + f) * CH;
    float er = 0.f, ei = 0.f;
    #pragma unroll
    for (int c = 0; c < 8; ++c) {
        float2 xv = Xp[c];
        float2 wv = wp[c];
        er += xv.x * wv.x - xv.y * wv.y;
        ei += xv.x * wv.y + xv.y * wv.x;
    }
    Xe[((size_t)b * NF + n) * FP + f] = make_float2(er, ei);
}

// ---------------- ISTFT: inverse DFT per frame + windowed atomic overlap-add ----------------
__global__ __launch_bounds__(256) void k_istft(const float2* __restrict__ Xe,
                                               const float* __restrict__ tw,
                                               float* __restrict__ y) {
    __shared__ float2 xr[256];
    __shared__ float tc[512], ts[512];
    int blk = blockIdx.x;
    int m = blk % NF, b = blk / NF;
    int tid = threadIdx.x;
    xr[tid] = Xe[((size_t)b * NF + m) * FP + tid];
    for (int t = tid; t < 512; t += 256) { tc[t] = tw[t]; ts[t] = tw[512 + t]; }
    __syncthreads();
    float nyq = xr[255].x;  // bin 256: irfft uses real part only
    #pragma unroll
    for (int tt = 0; tt < 2; ++tt) {
        int t = tid + tt * 256;
        float acc = (t & 1) ? -nyq : nyq;
        for (int k = 1; k < 256; ++k) {      // bins 1..255, factor 2
            int id = (k * t) & 511;
            float2 xv = xr[k - 1];
            acc += 2.f * (xv.x * tc[id] - xv.y * ts[id]);
        }
        float val = acc * (1.f / 512.f) * tw[1024 + t];
        atomicAdd(&y[(size_t)b * YLEN + m * HOP + t], val);
    }
}

// ---------------- normalize by window sum, trim padding ----------------
__global__ __launch_bounds__(256) void k_out(const float* __restrict__ y,
                                             const float* __restrict__ tw,
                                             float* __restrict__ out) {
    int i = blockIdx.x * blockDim.x + threadIdx.x;
    if (i >= BATCH * TLEN) return;
    int b = i / TLEN;
    int t = i % TLEN;
    int p = t + PADW;
    float wsum = 0.f;
    int m0 = p >> 7;
    #pragma unroll
    for (int dm = 0; dm < 4; ++dm) {
        int mm = m0 - dm;
        if (mm >= 0 && mm < NF) {
            float wv = tw[1024 + (p - mm * HOP)];
            wsum += wv * wv;
        }
    }
    out[i] = y[(size_t)b * YLEN + p] / fmaxf(wsum, 1e-10f);
}

extern "C" void kernel_launch(void* const* d_in, const int* in_sizes, int n_in,
                              void* d_out, int out_size, void* d_ws, size_t ws_size,
                              hipStream_t stream) {
    const float* x  = (const float*)d_in[0];
    const float* w1 = (const float*)d_in[1];
    const float* b1 = (const float*)d_in[2];
    const float* w2 = (const float*)d_in[3];
    const float* b2 = (const float*)d_in[4];

    float* ws = (float*)d_ws;
    // workspace layout (floats)
    size_t off = 0;
    float*  tw   = ws + off; off += 1536;
    float2* X    = (float2*)(ws + off); off += (size_t)BATCH * FP * NF * CH * 2;   // 16,416,768
    float*  feat = ws + off; off += (size_t)BATCH * NF * FP;                        // 1,026,048
    float*  h    = ws + off; off += (size_t)BATCH * NF * HID;                       // 2,052,096
    float*  mo   = ws + off; off += (size_t)BATCH * NF * HID;                       // 2,052,096
    float2* wc   = (float2*)(ws + off); off += (size_t)BATCH * FP * CH * 2;         // 32,768
    float2* Xe   = (float2*)(ws + off); off += (size_t)BATCH * NF * FP * 2;         // 2,052,096
    float*  y    = ws + off; off += (size_t)BATCH * YLEN;                           // 516,096

    hipMemsetAsync(y, 0, (size_t)BATCH * YLEN * sizeof(float), stream);

    k_tables<<<2, 256, 0, stream>>>(tw);
    k_stft<<<BATCH * CH * NF, 256, 0, stream>>>(x, tw, X, feat);
    k_mlp1<<<(BATCH * NF / 8) * 2, 256, 0, stream>>>(feat, w1, b1, h);
    k_mlp2<<<(BATCH * NF / 8) * 2, 256, 0, stream>>>(h, w2, b2, mo);
    k_cov_solve<<<BATCH * FP, 64, 0, stream>>>(X, mo, wc);
    k_beamform<<<BATCH * NF, 256, 0, stream>>>(X, wc, Xe);
    k_istft<<<BATCH * NF, 256, 0, stream>>>(Xe, tw, y);
    k_out<<<(BATCH * TLEN + 255) / 256, 256, 0, stream>>>(y, tw, (float*)d_out);
}

// Round 2
// 556.319 us; speedup vs baseline: 3.1631x; 3.1631x over previous
//
#include <hip/hip_runtime.h>
#include <math.h>

#define NFFT 512
#define HOP  128
#define PADW 256
#define TLEN 64000
#define NF   501
#define FP   256
#define CH   8
#define BATCH 8
#define HID  512
#define YLEN 64512  // NFFT + HOP*(NF-1)
#define FPB  8      // frames per block
#define NGRP 63     // ceil(NF/FPB)

// ---------------- tables: hann window only (twiddles via recurrence now) ----------------
__global__ void k_tables(float* tw) {
    int j = threadIdx.x + blockIdx.x * blockDim.x;
    if (j < 512) {
        float ang = (float)(2.0 * M_PI * (double)j / 512.0);
        tw[j] = 0.5f - 0.5f * cosf(ang);
    }
}

// ---------------- STFT: block = (b,c,frame-group of 8); thread = bin k=tid+1 ----------------
// Rotation recurrence, no twiddle table in inner loop; 8 frames amortize rotation cost.
__global__ __launch_bounds__(256) void k_stft(const float* __restrict__ x,
                                              const float* __restrict__ tw,
                                              float2* __restrict__ X,
                                              float* __restrict__ feat) {
    __shared__ float s[FPB][512];
    int blk = blockIdx.x;
    int g = blk % NGRP;
    int bc = blk / NGRP;
    int c = bc % CH, b = bc / CH;
    int m0 = g * FPB;
    int tid = threadIdx.x;
    const float* xp = x + (size_t)(b * CH + c) * TLEN;
    for (int i = tid; i < FPB * 512; i += 256) {
        int fr = i >> 9, t = i & 511;
        int j = (m0 + fr) * HOP + t - PADW;   // reflect pad (handles padded tail frames too)
        if (j < 0) j = -j;
        if (j >= TLEN) j = 2 * (TLEN - 1) - j;
        s[fr][t] = xp[j] * tw[t];
    }
    __syncthreads();

    int k = tid + 1;  // bins 1..256
    float sa, sc;
    sincosf((float)k * (float)(2.0 * M_PI / 512.0), &sa, &sc);
    float stepc = sc, steps = -sa;            // e^{-i 2pi k/512}

    float ar[FPB], ai[FPB];
    #pragma unroll
    for (int f = 0; f < FPB; ++f) { ar[f] = 0.f; ai[f] = 0.f; }

    for (int t0 = 0; t0 < 512; t0 += 128) {
        float a0 = (float)((k * t0) & 511) * (float)(2.0 * M_PI / 512.0);
        float s0, c0;
        sincosf(a0, &s0, &c0);
        float cr = c0, ci = -s0;              // e^{-i a0}
        #pragma unroll 4
        for (int t = t0; t < t0 + 128; ++t) {
            #pragma unroll
            for (int f = 0; f < FPB; ++f) {
                float sv = s[f][t];
                ar[f] += sv * cr;
                ai[f] += sv * ci;
            }
            float ncr = cr * stepc - ci * steps;
            ci = cr * steps + ci * stepc;
            cr = ncr;
        }
    }

    int fbin = k - 1;
    #pragma unroll
    for (int fr = 0; fr < FPB; ++fr) {
        int m = m0 + fr;
        if (m < NF) {
            X[((size_t)(b * FP + fbin) * NF + m) * CH + c] = make_float2(ar[fr], ai[fr]);
            if (c == 0)
                feat[((size_t)b * NF + m) * FP + fbin] = sqrtf(ar[fr] * ar[fr] + ai[fr] * ai[fr]);
        }
    }
}

// ---------------- MLP layer 1: h = relu(feat @ w1 + b1) ----------------
__global__ __launch_bounds__(256) void k_mlp1(const float* __restrict__ feat,
                                              const float* __restrict__ w1,
                                              const float* __restrict__ b1,
                                              float* __restrict__ h) {
    __shared__ float fr[8][FP];
    int rb = blockIdx.x >> 1, jc = blockIdx.x & 1;
    int tid = threadIdx.x;
    int row0 = rb * 8;
    for (int i = tid; i < 8 * FP; i += 256)
        fr[i >> 8][i & 255] = feat[(size_t)row0 * FP + i];
    __syncthreads();
    int j = jc * 256 + tid;
    float bj = b1[j];
    float acc[8];
    #pragma unroll
    for (int r = 0; r < 8; ++r) acc[r] = bj;
    for (int f = 0; f < FP; ++f) {
        float wv = w1[(size_t)f * HID + j];
        #pragma unroll
        for (int r = 0; r < 8; ++r) acc[r] += fr[r][f] * wv;
    }
    #pragma unroll
    for (int r = 0; r < 8; ++r)
        h[(size_t)(row0 + r) * HID + j] = fmaxf(acc[r], 0.f);
}

// ---------------- MLP layer 2: m = sigmoid(h @ w2 + b2) ----------------
__global__ __launch_bounds__(256) void k_mlp2(const float* __restrict__ h,
                                              const float* __restrict__ w2,
                                              const float* __restrict__ b2,
                                              float* __restrict__ mo) {
    __shared__ float hr[8][HID];
    int rb = blockIdx.x >> 1, jc = blockIdx.x & 1;
    int tid = threadIdx.x;
    int row0 = rb * 8;
    for (int i = tid; i < 8 * HID; i += 256)
        hr[i >> 9][i & 511] = h[(size_t)row0 * HID + i];
    __syncthreads();
    int j = jc * 256 + tid;
    float bj = b2[j];
    float acc[8];
    #pragma unroll
    for (int r = 0; r < 8; ++r) acc[r] = bj;
    for (int f = 0; f < HID; ++f) {
        float wv = w2[(size_t)f * HID + j];
        #pragma unroll
        for (int r = 0; r < 8; ++r) acc[r] += hr[r][f] * wv;
    }
    #pragma unroll
    for (int r = 0; r < 8; ++r)
        mo[(size_t)(row0 + r) * HID + j] = 1.f / (1.f + expf(-acc[r]));
}

// ---------------- covariance accumulate + 8x8 complex solve, per (b,f) ----------------
__global__ __launch_bounds__(64) void k_cov_solve(const float2* __restrict__ X,
                                                  const float* __restrict__ mo,
                                                  float2* __restrict__ wc) {
    int bf = blockIdx.x;
    int f = bf & 255;
    int b = bf >> 8;
    int lane = threadIdx.x;
    int c = lane >> 3, d = lane & 7;
    float ar = 0.f, ai = 0.f, rr = 0.f, ri = 0.f;
    const float2* Xb = X + (size_t)(b * FP + f) * NF * CH;
    const float* mb = mo + (size_t)b * NF * HID + f;
    for (int n = 0; n < NF; ++n) {
        float2 xc = Xb[n * CH + c];
        float2 xd = Xb[n * CH + d];
        float mt = mb[n * HID];
        float mn = mb[n * HID + FP];
        float pr = xc.x * xd.x + xc.y * xd.y;   // xc * conj(xd)
        float pi = xc.y * xd.x - xc.x * xd.y;
        float w = mt + mn;
        ar += w * pr; ai += w * pi;
        rr += mt * pr; ri += mt * pi;           // valid when d==0
    }
    __shared__ float2 A[8][8];
    __shared__ float2 rhs[8];
    __shared__ float2 sol[8];
    A[c][d] = make_float2(ar, ai);
    if (d == 0) rhs[c] = make_float2(rr, ri);
    __syncthreads();
    if (lane == 0) {
        for (int k = 0; k < 8; ++k) {
            float2 p = A[k][k];
            float ip = 1.f / (p.x * p.x + p.y * p.y);
            float invr = p.x * ip, invi = -p.y * ip;
            for (int i = k + 1; i < 8; ++i) {
                float2 aik = A[i][k];
                float fr2 = aik.x * invr - aik.y * invi;
                float fi2 = aik.x * invi + aik.y * invr;
                for (int jj = k; jj < 8; ++jj) {
                    float2 ak = A[k][jj];
                    A[i][jj].x -= fr2 * ak.x - fi2 * ak.y;
                    A[i][jj].y -= fr2 * ak.y + fi2 * ak.x;
                }
                rhs[i].x -= fr2 * rhs[k].x - fi2 * rhs[k].y;
                rhs[i].y -= fr2 * rhs[k].y + fi2 * rhs[k].x;
            }
        }
        for (int k = 7; k >= 0; --k) {
            float sr = rhs[k].x, si = rhs[k].y;
            for (int jj = k + 1; jj < 8; ++jj) {
                float2 ak = A[k][jj];
                float2 xj = sol[jj];
                sr -= ak.x * xj.x - ak.y * xj.y;
                si -= ak.x * xj.y + ak.y * xj.x;
            }
            float2 p = A[k][k];
            float ip = 1.f / (p.x * p.x + p.y * p.y);
            sol[k].x = (sr * p.x + si * p.y) * ip;
            sol[k].y = (si * p.x - sr * p.y) * ip;
        }
        for (int cc = 0; cc < 8; ++cc)
            wc[(size_t)(b * FP + f) * CH + cc] = make_float2(sol[cc].x, -sol[cc].y);
    }
}

// ---------------- beamform: Xe[b][n][f] = sum_c X[b,f,n,c] * wc[b,f,c] ----------------
__global__ __launch_bounds__(256) void k_beamform(const float2* __restrict__ X,
                                                  const float2* __restrict__ wc,
                                                  float2* __restrict__ Xe) {
    int blk = blockIdx.x;
    int n = blk % NF, b = blk / NF;
    int f = threadIdx.x;
    const float2* Xp = X + ((size_t)(b * FP + f) * NF + n) * CH;
    const float2* wp = wc + (size_t)(b * FP + f) * CH;
    float er = 0.f, ei = 0.f;
    #pragma unroll
    for (int c = 0; c < 8; ++c) {
        float2 xv = Xp[c];
        float2 wv = wp[c];
        er += xv.x * wv.x - xv.y * wv.y;
        ei += xv.x * wv.y + xv.y * wv.x;
    }
    Xe[((size_t)b * NF + n) * FP + f] = make_float2(er, ei);
}

// ---------------- ISTFT: block = (b, frame-group of 8); thread = output sample t ----------------
// Same rotation-recurrence scheme; 8 frames amortize rotation. Windowed atomic overlap-add.
__global__ __launch_bounds__(512) void k_istft(const float2* __restrict__ Xe,
                                               const float* __restrict__ tw,
                                               float* __restrict__ y) {
    __shared__ float2 xr[FPB][256];
    int blk = blockIdx.x;
    int g = blk % NGRP, b = blk / NGRP;
    int m0 = g * FPB;
    int tid = threadIdx.x;  // t = 0..511
    for (int i = tid; i < FPB * 256; i += 512) {
        int fr = i >> 8, kk = i & 255;
        int m = m0 + fr;
        xr[fr][kk] = (m < NF) ? Xe[((size_t)b * NF + m) * FP + kk] : make_float2(0.f, 0.f);
    }
    __syncthreads();

    int t = tid;
    float sa, sc;
    sincosf((float)t * (float)(2.0 * M_PI / 512.0), &sa, &sc);
    float stepc = sc, steps = sa;             // e^{+i 2pi t/512}

    float acc[FPB];
    #pragma unroll
    for (int f = 0; f < FPB; ++f) acc[f] = 0.f;

    for (int k0 = 1; k0 < 256; k0 += 128) {   // k = 1..255 in chunks (1..128, 129..255)
        float a0 = (float)((k0 * t) & 511) * (float)(2.0 * M_PI / 512.0);
        float s0, c0;
        sincosf(a0, &s0, &c0);
        float cr = c0, ci = s0;               // e^{+i a0}
        int kend = (k0 + 128 < 256) ? k0 + 128 : 256;
        #pragma unroll 4
        for (int k = k0; k < kend; ++k) {
            #pragma unroll
            for (int f = 0; f < FPB; ++f) {
                float2 xv = xr[f][k - 1];
                acc[f] += xv.x * cr - xv.y * ci;   // Re(X[k] e^{i theta})
            }
            float ncr = cr * stepc - ci * steps;
            ci = cr * steps + ci * stepc;
            cr = ncr;
        }
    }

    float nyqs = (t & 1) ? -1.f : 1.f;
    float wv = tw[t] * (1.f / 512.f);
    #pragma unroll
    for (int fr = 0; fr < FPB; ++fr) {
        int m = m0 + fr;
        if (m < NF) {
            float val = (2.f * acc[fr] + nyqs * xr[fr][255].x) * wv;
            atomicAdd(&y[(size_t)b * YLEN + m * HOP + t], val);
        }
    }
}

// ---------------- normalize by window sum, trim padding ----------------
__global__ __launch_bounds__(256) void k_out(const float* __restrict__ y,
                                             const float* __restrict__ tw,
                                             float* __restrict__ out) {
    int i = blockIdx.x * blockDim.x + threadIdx.x;
    if (i >= BATCH * TLEN) return;
    int b = i / TLEN;
    int t = i % TLEN;
    int p = t + PADW;
    float wsum = 0.f;
    int m0 = p >> 7;
    #pragma unroll
    for (int dm = 0; dm < 4; ++dm) {
        int mm = m0 - dm;
        if (mm >= 0 && mm < NF) {
            float wv = tw[p - mm * HOP];
            wsum += wv * wv;
        }
    }
    out[i] = y[(size_t)b * YLEN + p] / fmaxf(wsum, 1e-10f);
}

extern "C" void kernel_launch(void* const* d_in, const int* in_sizes, int n_in,
                              void* d_out, int out_size, void* d_ws, size_t ws_size,
                              hipStream_t stream) {
    const float* x  = (const float*)d_in[0];
    const float* w1 = (const float*)d_in[1];
    const float* b1 = (const float*)d_in[2];
    const float* w2 = (const float*)d_in[3];
    const float* b2 = (const float*)d_in[4];

    float* ws = (float*)d_ws;
    size_t off = 0;
    float*  tw   = ws + off; off += 512;
    float2* X    = (float2*)(ws + off); off += (size_t)BATCH * FP * NF * CH * 2;
    float*  feat = ws + off; off += (size_t)BATCH * NF * FP;
    float*  h    = ws + off; off += (size_t)BATCH * NF * HID;
    float*  mo   = ws + off; off += (size_t)BATCH * NF * HID;
    float2* wc   = (float2*)(ws + off); off += (size_t)BATCH * FP * CH * 2;
    float2* Xe   = (float2*)(ws + off); off += (size_t)BATCH * NF * FP * 2;
    float*  y    = ws + off; off += (size_t)BATCH * YLEN;

    hipMemsetAsync(y, 0, (size_t)BATCH * YLEN * sizeof(float), stream);

    k_tables<<<2, 256, 0, stream>>>(tw);
    k_stft<<<BATCH * CH * NGRP, 256, 0, stream>>>(x, tw, X, feat);
    k_mlp1<<<(BATCH * NF / 8) * 2, 256, 0, stream>>>(feat, w1, b1, h);
    k_mlp2<<<(BATCH * NF / 8) * 2, 256, 0, stream>>>(h, w2, b2, mo);
    k_cov_solve<<<BATCH * FP, 64, 0, stream>>>(X, mo, wc);
    k_beamform<<<BATCH * NF, 256, 0, stream>>>(X, wc, Xe);
    k_istft<<<BATCH * NGRP, 512, 0, stream>>>(Xe, tw, y);
    k_out<<<(BATCH * TLEN + 255) / 256, 256, 0, stream>>>(y, tw, (float*)d_out);
}

// Round 3
// 325.528 us; speedup vs baseline: 5.4057x; 1.7090x over previous
//
#include <hip/hip_runtime.h>
#include <math.h>

#define NFFT 512
#define HOP  128
#define PADW 256
#define TLEN 64000
#define NF   501
#define FP   256
#define CH   8
#define BATCH 8
#define HID  512
#define YLEN 64512  // NFFT + HOP*(NF-1)
#define FPB  8      // frames per block
#define NGRP 63     // ceil(NF/FPB)

// Y LDS index: [t1][j][fr] with j rotated by 2*t1 (bank spread) and row padded to 9 float2
__device__ __forceinline__ int Yidx(int t1, int j, int fr) {
    return (t1 * 32 + ((j + 2 * t1) & 31)) * 9 + fr;
}

// ---------------- tables: hann window ----------------
__global__ void k_tables(float* tw) {
    int j = threadIdx.x + blockIdx.x * blockDim.x;
    if (j < 512) {
        float ang = (float)(2.0 * M_PI * (double)j / 512.0);
        tw[j] = 0.5f - 0.5f * cosf(ang);
    }
}

// ---------------- STFT: two-stage Cooley-Tukey (512 = 16 x 32), 8 frames/block ----------------
// X layout: [b][n][c][f] float2 (f minor -> coalesced stores)
__global__ __launch_bounds__(256) void k_stft(const float* __restrict__ x,
                                              const float* __restrict__ tw,
                                              float2* __restrict__ X,
                                              float* __restrict__ feat) {
    __shared__ float sT[512][8];          // [t][frame]
    __shared__ float2 Yl[16 * 32 * 9];    // inner DFT-32 results
    int blk = blockIdx.x;
    int g = blk % NGRP;
    int bc = blk / NGRP;
    int c = bc % CH, b = bc / CH;
    int m0 = g * FPB;
    int tid = threadIdx.x;
    const float* xp = x + (size_t)(b * CH + c) * TLEN;

    // stage A: load 8 windowed frames, [t][fr] layout (conflict-free, t minor-ish)
    for (int i = tid; i < FPB * 512; i += 256) {
        int t = i >> 3, fr = i & 7;
        int j = (m0 + fr) * HOP + t - PADW;   // reflect pad
        if (j < 0) j = -j;
        if (j >= TLEN) j = 2 * (TLEN - 1) - j;
        sT[t][fr] = xp[j] * tw[t];
    }
    __syncthreads();

    // stage B: inner DFT-32: Y[t1][j] = sum_t2 s[t1+16*t2] e^{-i 2pi j t2/32}
    // thread = (j = tid>>3, q = tid&7), handles t1 = q and q+8, all 8 frames
    {
        int jj = tid >> 3, q = tid & 7;
        float sj, cj;
        sincosf((float)jj * (float)(2.0 * M_PI / 32.0), &sj, &cj);
        float stepc = cj, steps = -sj;        // e^{-i 2pi j/32}
        float y0r[8], y0i[8], y1r[8], y1i[8];
        #pragma unroll
        for (int fr = 0; fr < 8; ++fr) { y0r[fr] = 0.f; y0i[fr] = 0.f; y1r[fr] = 0.f; y1i[fr] = 0.f; }
        float cr = 1.f, ci = 0.f;
        #pragma unroll 4
        for (int t2 = 0; t2 < 32; ++t2) {
            const float4 a0 = *(const float4*)&sT[q + 16 * t2][0];
            const float4 a1 = *(const float4*)&sT[q + 16 * t2][4];
            const float4 b0 = *(const float4*)&sT[q + 8 + 16 * t2][0];
            const float4 b1 = *(const float4*)&sT[q + 8 + 16 * t2][4];
            float av[8] = {a0.x, a0.y, a0.z, a0.w, a1.x, a1.y, a1.z, a1.w};
            float bv[8] = {b0.x, b0.y, b0.z, b0.w, b1.x, b1.y, b1.z, b1.w};
            #pragma unroll
            for (int fr = 0; fr < 8; ++fr) {
                y0r[fr] += av[fr] * cr; y0i[fr] += av[fr] * ci;
                y1r[fr] += bv[fr] * cr; y1i[fr] += bv[fr] * ci;
            }
            float ncr = cr * stepc - ci * steps;
            ci = cr * steps + ci * stepc;
            cr = ncr;
        }
        #pragma unroll
        for (int fr = 0; fr < 8; ++fr) {
            Yl[Yidx(q, jj, fr)]     = make_float2(y0r[fr], y0i[fr]);
            Yl[Yidx(q + 8, jj, fr)] = make_float2(y1r[fr], y1i[fr]);
        }
    }
    __syncthreads();

    // stage C: X[k] = sum_t1 e^{-i 2pi k t1/512} Y[t1][k mod 32]; thread = bin k
    int k = tid + 1;
    int j = k & 31;
    float sk, ck;
    sincosf((float)k * (float)(2.0 * M_PI / 512.0), &sk, &ck);
    float stepc = ck, steps = -sk;            // e^{-i 2pi k/512}
    float xr_[8], xi_[8];
    #pragma unroll
    for (int fr = 0; fr < 8; ++fr) { xr_[fr] = 0.f; xi_[fr] = 0.f; }
    float cr = 1.f, ci = 0.f;
    #pragma unroll 4
    for (int t1 = 0; t1 < 16; ++t1) {
        #pragma unroll
        for (int fr = 0; fr < 8; ++fr) {
            float2 yv = Yl[Yidx(t1, j, fr)];
            xr_[fr] += yv.x * cr - yv.y * ci;
            xi_[fr] += yv.x * ci + yv.y * cr;
        }
        float ncr = cr * stepc - ci * steps;
        ci = cr * steps + ci * stepc;
        cr = ncr;
    }
    int fbin = k - 1;
    #pragma unroll
    for (int fr = 0; fr < 8; ++fr) {
        int m = m0 + fr;
        if (m < NF) {
            X[((size_t)(b * NF + m) * CH + c) * FP + fbin] = make_float2(xr_[fr], xi_[fr]);
            if (c == 0)
                feat[((size_t)b * NF + m) * FP + fbin] = sqrtf(xr_[fr] * xr_[fr] + xi_[fr] * xi_[fr]);
        }
    }
}

// ---------------- MLP layer 1: h = relu(feat @ w1 + b1) ----------------
__global__ __launch_bounds__(256) void k_mlp1(const float* __restrict__ feat,
                                              const float* __restrict__ w1,
                                              const float* __restrict__ b1,
                                              float* __restrict__ h) {
    __shared__ float fr[8][FP];
    int rb = blockIdx.x >> 1, jc = blockIdx.x & 1;
    int tid = threadIdx.x;
    int row0 = rb * 8;
    for (int i = tid; i < 8 * FP; i += 256)
        fr[i >> 8][i & 255] = feat[(size_t)row0 * FP + i];
    __syncthreads();
    int j = jc * 256 + tid;
    float bj = b1[j];
    float acc[8];
    #pragma unroll
    for (int r = 0; r < 8; ++r) acc[r] = bj;
    for (int f = 0; f < FP; ++f) {
        float wv = w1[(size_t)f * HID + j];
        #pragma unroll
        for (int r = 0; r < 8; ++r) acc[r] += fr[r][f] * wv;
    }
    #pragma unroll
    for (int r = 0; r < 8; ++r)
        h[(size_t)(row0 + r) * HID + j] = fmaxf(acc[r], 0.f);
}

// ---------------- MLP layer 2: m = sigmoid(h @ w2 + b2) ----------------
__global__ __launch_bounds__(256) void k_mlp2(const float* __restrict__ h,
                                              const float* __restrict__ w2,
                                              const float* __restrict__ b2,
                                              float* __restrict__ mo) {
    __shared__ float hr[8][HID];
    int rb = blockIdx.x >> 1, jc = blockIdx.x & 1;
    int tid = threadIdx.x;
    int row0 = rb * 8;
    for (int i = tid; i < 8 * HID; i += 256)
        hr[i >> 9][i & 511] = h[(size_t)row0 * HID + i];
    __syncthreads();
    int j = jc * 256 + tid;
    float bj = b2[j];
    float acc[8];
    #pragma unroll
    for (int r = 0; r < 8; ++r) acc[r] = bj;
    for (int f = 0; f < HID; ++f) {
        float wv = w2[(size_t)f * HID + j];
        #pragma unroll
        for (int r = 0; r < 8; ++r) acc[r] += hr[r][f] * wv;
    }
    #pragma unroll
    for (int r = 0; r < 8; ++r)
        mo[(size_t)(row0 + r) * HID + j] = 1.f / (1.f + expf(-acc[r]));
}

// ---------------- covariance + solve: block = (b, group of 8 f), tid = c*64+d*8+fl ----------------
__global__ __launch_bounds__(512) void k_cov_solve(const float2* __restrict__ X,
                                                   const float* __restrict__ mo,
                                                   float2* __restrict__ wc) {
    int b = blockIdx.x >> 5, fg = blockIdx.x & 31;
    int f0 = fg * 8;
    int tid = threadIdx.x;
    int c = tid >> 6, d = (tid >> 3) & 7, fl = tid & 7;
    int f = f0 + fl;
    float ar = 0.f, ai = 0.f, rr = 0.f, ri = 0.f;
    const float2* Xb = X + (size_t)b * NF * CH * FP;
    const float* mb = mo + (size_t)b * NF * HID;
    for (int n = 0; n < NF; ++n) {
        float2 xc = Xb[(size_t)(n * CH + c) * FP + f];
        float2 xd = Xb[(size_t)(n * CH + d) * FP + f];
        float mt = mb[(size_t)n * HID + f];
        float mn = mb[(size_t)n * HID + FP + f];
        float pr = xc.x * xd.x + xc.y * xd.y;   // xc * conj(xd)
        float pi = xc.y * xd.x - xc.x * xd.y;
        float w = mt + mn;
        ar += w * pr;  ai += w * pi;
        rr += mt * pr; ri += mt * pi;           // used when d==0
    }
    __shared__ float2 Am[8][73];   // 8 matrices, row-major 8x8 with i*9+j (padded)
    __shared__ float2 rh[8][8];
    __shared__ float2 sl[8][9];
    Am[fl][c * 9 + d] = make_float2(ar, ai);
    if (d == 0) rh[fl][c] = make_float2(rr, ri);
    __syncthreads();
    if (tid < 8) {
        int ln = tid;
        float2* A = Am[ln];
        float2* r = rh[ln];
        float2* sol = sl[ln];
        for (int kk = 0; kk < 8; ++kk) {
            float2 p = A[kk * 9 + kk];
            float ip = 1.f / (p.x * p.x + p.y * p.y);
            float invr = p.x * ip, invi = -p.y * ip;
            for (int i = kk + 1; i < 8; ++i) {
                float2 aik = A[i * 9 + kk];
                float fr2 = aik.x * invr - aik.y * invi;
                float fi2 = aik.x * invi + aik.y * invr;
                for (int jj = kk; jj < 8; ++jj) {
                    float2 ak = A[kk * 9 + jj];
                    A[i * 9 + jj].x -= fr2 * ak.x - fi2 * ak.y;
                    A[i * 9 + jj].y -= fr2 * ak.y + fi2 * ak.x;
                }
                r[i].x -= fr2 * r[kk].x - fi2 * r[kk].y;
                r[i].y -= fr2 * r[kk].y + fi2 * r[kk].x;
            }
        }
        for (int kk = 7; kk >= 0; --kk) {
            float sr = r[kk].x, si = r[kk].y;
            for (int jj = kk + 1; jj < 8; ++jj) {
                float2 ak = A[kk * 9 + jj];
                float2 xj = sol[jj];
                sr -= ak.x * xj.x - ak.y * xj.y;
                si -= ak.x * xj.y + ak.y * xj.x;
            }
            float2 p = A[kk * 9 + kk];
            float ip = 1.f / (p.x * p.x + p.y * p.y);
            sol[kk].x = (sr * p.x + si * p.y) * ip;
            sol[kk].y = (si * p.x - sr * p.y) * ip;
        }
        for (int cc = 0; cc < 8; ++cc)   // wc layout [b][c][f], store conj
            wc[((size_t)b * CH + cc) * FP + f0 + ln] = make_float2(sol[cc].x, -sol[cc].y);
    }
}

// ---------------- beamform: Xe[b][n][f] = sum_c X[b,n,c,f] * wc[b,c,f] ----------------
__global__ __launch_bounds__(256) void k_beamform(const float2* __restrict__ X,
                                                  const float2* __restrict__ wc,
                                                  float2* __restrict__ Xe) {
    int blk = blockIdx.x;
    int n = blk % NF, b = blk / NF;
    int f = threadIdx.x;
    float er = 0.f, ei = 0.f;
    #pragma unroll
    for (int c = 0; c < 8; ++c) {
        float2 xv = X[((size_t)(b * NF + n) * CH + c) * FP + f];
        float2 wv = wc[((size_t)b * CH + c) * FP + f];
        er += xv.x * wv.x - xv.y * wv.y;
        ei += xv.x * wv.y + xv.y * wv.x;
    }
    Xe[((size_t)b * NF + n) * FP + f] = make_float2(er, ei);
}

// ---------------- ISTFT: rotation-recurrence iDFT, 8 frames/block, atomic overlap-add ----------------
__global__ __launch_bounds__(512) void k_istft(const float2* __restrict__ Xe,
                                               const float* __restrict__ tw,
                                               float* __restrict__ y) {
    __shared__ float2 xr[FPB][256];
    int blk = blockIdx.x;
    int g = blk % NGRP, b = blk / NGRP;
    int m0 = g * FPB;
    int tid = threadIdx.x;  // t = 0..511
    for (int i = tid; i < FPB * 256; i += 512) {
        int fr = i >> 8, kk = i & 255;
        int m = m0 + fr;
        xr[fr][kk] = (m < NF) ? Xe[((size_t)b * NF + m) * FP + kk] : make_float2(0.f, 0.f);
    }
    __syncthreads();

    int t = tid;
    float sa, sc;
    sincosf((float)t * (float)(2.0 * M_PI / 512.0), &sa, &sc);
    float stepc = sc, steps = sa;             // e^{+i 2pi t/512}

    float acc[FPB];
    #pragma unroll
    for (int f = 0; f < FPB; ++f) acc[f] = 0.f;

    for (int k0 = 1; k0 < 256; k0 += 128) {
        float a0 = (float)((k0 * t) & 511) * (float)(2.0 * M_PI / 512.0);
        float s0, c0;
        sincosf(a0, &s0, &c0);
        float cr = c0, ci = s0;
        int kend = (k0 + 128 < 256) ? k0 + 128 : 256;
        #pragma unroll 4
        for (int k = k0; k < kend; ++k) {
            #pragma unroll
            for (int f = 0; f < FPB; ++f) {
                float2 xv = xr[f][k - 1];
                acc[f] += xv.x * cr - xv.y * ci;
            }
            float ncr = cr * stepc - ci * steps;
            ci = cr * steps + ci * stepc;
            cr = ncr;
        }
    }

    float nyqs = (t & 1) ? -1.f : 1.f;
    float wv = tw[t] * (1.f / 512.f);
    #pragma unroll
    for (int fr = 0; fr < FPB; ++fr) {
        int m = m0 + fr;
        if (m < NF) {
            float val = (2.f * acc[fr] + nyqs * xr[fr][255].x) * wv;
            atomicAdd(&y[(size_t)b * YLEN + m * HOP + t], val);
        }
    }
}

// ---------------- normalize by window sum, trim padding ----------------
__global__ __launch_bounds__(256) void k_out(const float* __restrict__ y,
                                             const float* __restrict__ tw,
                                             float* __restrict__ out) {
    int i = blockIdx.x * blockDim.x + threadIdx.x;
    if (i >= BATCH * TLEN) return;
    int b = i / TLEN;
    int t = i % TLEN;
    int p = t + PADW;
    float wsum = 0.f;
    int m0 = p >> 7;
    #pragma unroll
    for (int dm = 0; dm < 4; ++dm) {
        int mm = m0 - dm;
        if (mm >= 0 && mm < NF) {
            float wv = tw[p - mm * HOP];
            wsum += wv * wv;
        }
    }
    out[i] = y[(size_t)b * YLEN + p] / fmaxf(wsum, 1e-10f);
}

extern "C" void kernel_launch(void* const* d_in, const int* in_sizes, int n_in,
                              void* d_out, int out_size, void* d_ws, size_t ws_size,
                              hipStream_t stream) {
    const float* x  = (const float*)d_in[0];
    const float* w1 = (const float*)d_in[1];
    const float* b1 = (const float*)d_in[2];
    const float* w2 = (const float*)d_in[3];
    const float* b2 = (const float*)d_in[4];

    float* ws = (float*)d_ws;
    size_t off = 0;
    float*  tw   = ws + off; off += 512;
    float2* X    = (float2*)(ws + off); off += (size_t)BATCH * FP * NF * CH * 2;
    float*  feat = ws + off; off += (size_t)BATCH * NF * FP;
    float*  h    = ws + off; off += (size_t)BATCH * NF * HID;
    float*  mo   = ws + off; off += (size_t)BATCH * NF * HID;
    float2* wc   = (float2*)(ws + off); off += (size_t)BATCH * FP * CH * 2;
    float2* Xe   = (float2*)(ws + off); off += (size_t)BATCH * NF * FP * 2;
    float*  y    = ws + off; off += (size_t)BATCH * YLEN;

    hipMemsetAsync(y, 0, (size_t)BATCH * YLEN * sizeof(float), stream);

    k_tables<<<2, 256, 0, stream>>>(tw);
    k_stft<<<BATCH * CH * NGRP, 256, 0, stream>>>(x, tw, X, feat);
    k_mlp1<<<(BATCH * NF / 8) * 2, 256, 0, stream>>>(feat, w1, b1, h);
    k_mlp2<<<(BATCH * NF / 8) * 2, 256, 0, stream>>>(h, w2, b2, mo);
    k_cov_solve<<<BATCH * 32, 512, 0, stream>>>(X, mo, wc);
    k_beamform<<<BATCH * NF, 256, 0, stream>>>(X, wc, Xe);
    k_istft<<<BATCH * NGRP, 512, 0, stream>>>(Xe, tw, y);
    k_out<<<(BATCH * TLEN + 255) / 256, 256, 0, stream>>>(y, tw, (float*)d_out);
}

// Round 4
// 293.790 us; speedup vs baseline: 5.9896x; 1.1080x over previous
//
#include <hip/hip_runtime.h>
#include <math.h>

#define NFFT 512
#define HOP  128
#define PADW 256
#define TLEN 64000
#define NF   501
#define FP   256
#define CH   8
#define BATCH 8
#define HID  512
#define YLEN 64512  // NFFT + HOP*(NF-1)
#define FPB  8      // frames per block
#define NGRP 63     // ceil(NF/FPB)
#define NCK  5      // cov n-chunks
#define CKLEN 101   // ceil(NF/NCK)

// Y LDS index for stft: [t1][j][fr], j rotated by 2*t1, row padded to 9 float2
__device__ __forceinline__ int Yidx(int t1, int j, int fr) {
    return (t1 * 32 + ((j + 2 * t1) & 31)) * 9 + fr;
}

// ---------------- tables: hann window ----------------
__global__ void k_tables(float* tw) {
    int j = threadIdx.x + blockIdx.x * blockDim.x;
    if (j < 512) {
        float ang = (float)(2.0 * M_PI * (double)j / 512.0);
        tw[j] = 0.5f - 0.5f * cosf(ang);
    }
}

// ---------------- STFT: two-stage Cooley-Tukey (512 = 16 x 32), 8 frames/block ----------------
__global__ __launch_bounds__(256) void k_stft(const float* __restrict__ x,
                                              const float* __restrict__ tw,
                                              float2* __restrict__ X,
                                              float* __restrict__ feat) {
    __shared__ float sT[512][8];          // [t][frame]
    __shared__ float2 Yl[16 * 32 * 9];    // inner DFT-32 results
    int blk = blockIdx.x;
    int g = blk % NGRP;
    int bc = blk / NGRP;
    int c = bc % CH, b = bc / CH;
    int m0 = g * FPB;
    int tid = threadIdx.x;
    const float* xp = x + (size_t)(b * CH + c) * TLEN;

    for (int i = tid; i < FPB * 512; i += 256) {
        int t = i >> 3, fr = i & 7;
        int j = (m0 + fr) * HOP + t - PADW;   // reflect pad
        if (j < 0) j = -j;
        if (j >= TLEN) j = 2 * (TLEN - 1) - j;
        sT[t][fr] = xp[j] * tw[t];
    }
    __syncthreads();

    // stage B: inner DFT-32
    {
        int jj = tid >> 3, q = tid & 7;
        float sj, cj;
        sincosf((float)jj * (float)(2.0 * M_PI / 32.0), &sj, &cj);
        float stepc = cj, steps = -sj;        // e^{-i 2pi j/32}
        float y0r[8], y0i[8], y1r[8], y1i[8];
        #pragma unroll
        for (int fr = 0; fr < 8; ++fr) { y0r[fr] = 0.f; y0i[fr] = 0.f; y1r[fr] = 0.f; y1i[fr] = 0.f; }
        float cr = 1.f, ci = 0.f;
        #pragma unroll 4
        for (int t2 = 0; t2 < 32; ++t2) {
            const float4 a0 = *(const float4*)&sT[q + 16 * t2][0];
            const float4 a1 = *(const float4*)&sT[q + 16 * t2][4];
            const float4 b0 = *(const float4*)&sT[q + 8 + 16 * t2][0];
            const float4 b1 = *(const float4*)&sT[q + 8 + 16 * t2][4];
            float av[8] = {a0.x, a0.y, a0.z, a0.w, a1.x, a1.y, a1.z, a1.w};
            float bv[8] = {b0.x, b0.y, b0.z, b0.w, b1.x, b1.y, b1.z, b1.w};
            #pragma unroll
            for (int fr = 0; fr < 8; ++fr) {
                y0r[fr] += av[fr] * cr; y0i[fr] += av[fr] * ci;
                y1r[fr] += bv[fr] * cr; y1i[fr] += bv[fr] * ci;
            }
            float ncr = cr * stepc - ci * steps;
            ci = cr * steps + ci * stepc;
            cr = ncr;
        }
        #pragma unroll
        for (int fr = 0; fr < 8; ++fr) {
            Yl[Yidx(q, jj, fr)]     = make_float2(y0r[fr], y0i[fr]);
            Yl[Yidx(q + 8, jj, fr)] = make_float2(y1r[fr], y1i[fr]);
        }
    }
    __syncthreads();

    // stage C: combine
    int k = tid + 1;
    int j = k & 31;
    float sk, ck;
    sincosf((float)k * (float)(2.0 * M_PI / 512.0), &sk, &ck);
    float stepc = ck, steps = -sk;            // e^{-i 2pi k/512}
    float xr_[8], xi_[8];
    #pragma unroll
    for (int fr = 0; fr < 8; ++fr) { xr_[fr] = 0.f; xi_[fr] = 0.f; }
    float cr = 1.f, ci = 0.f;
    #pragma unroll 4
    for (int t1 = 0; t1 < 16; ++t1) {
        #pragma unroll
        for (int fr = 0; fr < 8; ++fr) {
            float2 yv = Yl[Yidx(t1, j, fr)];
            xr_[fr] += yv.x * cr - yv.y * ci;
            xi_[fr] += yv.x * ci + yv.y * cr;
        }
        float ncr = cr * stepc - ci * steps;
        ci = cr * steps + ci * stepc;
        cr = ncr;
    }
    int fbin = k - 1;
    #pragma unroll
    for (int fr = 0; fr < 8; ++fr) {
        int m = m0 + fr;
        if (m < NF) {
            X[((size_t)(b * NF + m) * CH + c) * FP + fbin] = make_float2(xr_[fr], xi_[fr]);
            if (c == 0)
                feat[((size_t)b * NF + m) * FP + fbin] = sqrtf(xr_[fr] * xr_[fr] + xi_[fr] * xi_[fr]);
        }
    }
}

// ---------------- MLP layer 1 ----------------
__global__ __launch_bounds__(256) void k_mlp1(const float* __restrict__ feat,
                                              const float* __restrict__ w1,
                                              const float* __restrict__ b1,
                                              float* __restrict__ h) {
    __shared__ float fr[8][FP];
    int rb = blockIdx.x >> 1, jc = blockIdx.x & 1;
    int tid = threadIdx.x;
    int row0 = rb * 8;
    for (int i = tid; i < 8 * FP; i += 256)
        fr[i >> 8][i & 255] = feat[(size_t)row0 * FP + i];
    __syncthreads();
    int j = jc * 256 + tid;
    float bj = b1[j];
    float acc[8];
    #pragma unroll
    for (int r = 0; r < 8; ++r) acc[r] = bj;
    for (int f = 0; f < FP; ++f) {
        float wv = w1[(size_t)f * HID + j];
        #pragma unroll
        for (int r = 0; r < 8; ++r) acc[r] += fr[r][f] * wv;
    }
    #pragma unroll
    for (int r = 0; r < 8; ++r)
        h[(size_t)(row0 + r) * HID + j] = fmaxf(acc[r], 0.f);
}

// ---------------- MLP layer 2 ----------------
__global__ __launch_bounds__(256) void k_mlp2(const float* __restrict__ h,
                                              const float* __restrict__ w2,
                                              const float* __restrict__ b2,
                                              float* __restrict__ mo) {
    __shared__ float hr[8][HID];
    int rb = blockIdx.x >> 1, jc = blockIdx.x & 1;
    int tid = threadIdx.x;
    int row0 = rb * 8;
    for (int i = tid; i < 8 * HID; i += 256)
        hr[i >> 9][i & 511] = h[(size_t)row0 * HID + i];
    __syncthreads();
    int j = jc * 256 + tid;
    float bj = b2[j];
    float acc[8];
    #pragma unroll
    for (int r = 0; r < 8; ++r) acc[r] = bj;
    for (int f = 0; f < HID; ++f) {
        float wv = w2[(size_t)f * HID + j];
        #pragma unroll
        for (int r = 0; r < 8; ++r) acc[r] += hr[r][f] * wv;
    }
    #pragma unroll
    for (int r = 0; r < 8; ++r)
        mo[(size_t)(row0 + r) * HID + j] = 1.f / (1.f + expf(-acc[r]));
}

// ---------------- covariance partial sums: block = (b, fgroup, nchunk) ----------------
__global__ __launch_bounds__(512) void k_cov_part(const float2* __restrict__ X,
                                                  const float* __restrict__ mo,
                                                  float4* __restrict__ part) {
    int blk = blockIdx.x;
    int nc = blk % NCK;
    int fg = (blk / NCK) % 32;
    int b  = blk / (NCK * 32);
    int tid = threadIdx.x;
    int c = tid >> 6, d = (tid >> 3) & 7, fl = tid & 7;
    int f = fg * 8 + fl;
    int n0 = nc * CKLEN;
    int n1 = n0 + CKLEN; if (n1 > NF) n1 = NF;
    float ar = 0.f, ai = 0.f, rr = 0.f, ri = 0.f;
    const float2* Xb = X + (size_t)b * NF * CH * FP;
    const float* mb = mo + (size_t)b * NF * HID;
    for (int n = n0; n < n1; ++n) {
        float2 xc = Xb[(size_t)(n * CH + c) * FP + f];
        float2 xd = Xb[(size_t)(n * CH + d) * FP + f];
        float mt = mb[(size_t)n * HID + f];
        float mn = mb[(size_t)n * HID + FP + f];
        float pr = xc.x * xd.x + xc.y * xd.y;   // xc * conj(xd)
        float pi = xc.y * xd.x - xc.x * xd.y;
        float w = mt + mn;
        ar += w * pr;  ai += w * pi;
        rr += mt * pr; ri += mt * pi;
    }
    part[(size_t)blk * 512 + tid] = make_float4(ar, ai, rr, ri);
}

// ---------------- reduce partials + 8x8 complex solve: block = (b, fgroup) ----------------
__global__ __launch_bounds__(512) void k_cov_solve2(const float4* __restrict__ part,
                                                    float2* __restrict__ wc) {
    int blk = blockIdx.x;          // b*32 + fg
    int f0 = (blk & 31) * 8;
    int b = blk >> 5;
    int tid = threadIdx.x;
    int c = tid >> 6, d = (tid >> 3) & 7, fl = tid & 7;
    const float4* p = part + (size_t)blk * NCK * 512;
    float ar = 0.f, ai = 0.f, rr = 0.f, ri = 0.f;
    #pragma unroll
    for (int nc = 0; nc < NCK; ++nc) {
        float4 v = p[nc * 512 + tid];
        ar += v.x; ai += v.y; rr += v.z; ri += v.w;
    }
    __shared__ float2 Am[8][73];
    __shared__ float2 rh[8][8];
    __shared__ float2 sl[8][9];
    Am[fl][c * 9 + d] = make_float2(ar, ai);
    if (d == 0) rh[fl][c] = make_float2(rr, ri);
    __syncthreads();
    if (tid < 8) {
        int ln = tid;
        float2* A = Am[ln];
        float2* r = rh[ln];
        float2* sol = sl[ln];
        for (int kk = 0; kk < 8; ++kk) {
            float2 pp = A[kk * 9 + kk];
            float ip = 1.f / (pp.x * pp.x + pp.y * pp.y);
            float invr = pp.x * ip, invi = -pp.y * ip;
            for (int i = kk + 1; i < 8; ++i) {
                float2 aik = A[i * 9 + kk];
                float fr2 = aik.x * invr - aik.y * invi;
                float fi2 = aik.x * invi + aik.y * invr;
                for (int jj = kk; jj < 8; ++jj) {
                    float2 ak = A[kk * 9 + jj];
                    A[i * 9 + jj].x -= fr2 * ak.x - fi2 * ak.y;
                    A[i * 9 + jj].y -= fr2 * ak.y + fi2 * ak.x;
                }
                r[i].x -= fr2 * r[kk].x - fi2 * r[kk].y;
                r[i].y -= fr2 * r[kk].y + fi2 * r[kk].x;
            }
        }
        for (int kk = 7; kk >= 0; --kk) {
            float sr = r[kk].x, si = r[kk].y;
            for (int jj = kk + 1; jj < 8; ++jj) {
                float2 ak = A[kk * 9 + jj];
                float2 xj = sol[jj];
                sr -= ak.x * xj.x - ak.y * xj.y;
                si -= ak.x * xj.y + ak.y * xj.x;
            }
            float2 pp = A[kk * 9 + kk];
            float ip = 1.f / (pp.x * pp.x + pp.y * pp.y);
            sol[kk].x = (sr * pp.x + si * pp.y) * ip;
            sol[kk].y = (si * pp.x - sr * pp.y) * ip;
        }
        for (int cc = 0; cc < 8; ++cc)   // wc layout [b][c][f], store conj
            wc[((size_t)b * CH + cc) * FP + f0 + ln] = make_float2(sol[cc].x, -sol[cc].y);
    }
}

// ---------------- beamform ----------------
__global__ __launch_bounds__(256) void k_beamform(const float2* __restrict__ X,
                                                  const float2* __restrict__ wc,
                                                  float2* __restrict__ Xe) {
    int blk = blockIdx.x;
    int n = blk % NF, b = blk / NF;
    int f = threadIdx.x;
    float er = 0.f, ei = 0.f;
    #pragma unroll
    for (int c = 0; c < 8; ++c) {
        float2 xv = X[((size_t)(b * NF + n) * CH + c) * FP + f];
        float2 wv = wc[((size_t)b * CH + c) * FP + f];
        er += xv.x * wv.x - xv.y * wv.y;
        ei += xv.x * wv.y + xv.y * wv.x;
    }
    Xe[((size_t)b * NF + n) * FP + f] = make_float2(er, ei);
}

// ---------------- ISTFT: real-pair + two-stage (512 = 16 x 32) iDFT ----------------
// Frames paired: z = y_a + i*y_b -> one complex iDFT per pair (4 pairs = 8 frames/block).
__global__ __launch_bounds__(512) void k_istft(const float2* __restrict__ Xe,
                                               const float* __restrict__ tw,
                                               float* __restrict__ y) {
    __shared__ float2 Zp[4 * 512];          // [sig][k] Hermitian-combined spectra
    __shared__ float2 Gl[16 * 32 * 5];      // [k1][tau][sig] pad 5
    int blk = blockIdx.x;
    int g = blk % NGRP, b = blk / NGRP;
    int m0 = g * FPB;
    int tid = threadIdx.x;

    if (tid < 4) Zp[tid * 512] = make_float2(0.f, 0.f);   // k = 0 (DC dropped)
    for (int i = tid; i < 4 * 256; i += 512) {
        int sig = i >> 8, kp = i & 255;     // bin kp -> k = kp+1
        int ma = m0 + 2 * sig, mb_ = ma + 1;
        float2 Xa = (ma < NF) ? Xe[((size_t)b * NF + ma) * FP + kp] : make_float2(0.f, 0.f);
        float2 Xb = (mb_ < NF) ? Xe[((size_t)b * NF + mb_) * FP + kp] : make_float2(0.f, 0.f);
        int k = kp + 1;
        if (k == 256) {
            Zp[sig * 512 + 256] = make_float2(Xa.x, Xb.x);   // Nyquist: real parts only
        } else {
            Zp[sig * 512 + k]       = make_float2(Xa.x - Xb.y, Xa.y + Xb.x);       // Za + i Zb
            Zp[sig * 512 + 512 - k] = make_float2(Xa.x + Xb.y, Xb.x - Xa.y);       // conj(Za) + i conj(Zb)
        }
    }
    __syncthreads();

    // stage 1: G[k1][tau] = sum_{k2} Zp[k1+16*k2] e^{+i 2pi k2 tau/32}
    {
        int k1 = tid >> 5, tau = tid & 31;
        float sa, ca;
        sincosf((float)tau * (float)(2.0 * M_PI / 32.0), &sa, &ca);
        float stepc = ca, steps = sa;
        float gr[4], gi[4];
        #pragma unroll
        for (int s = 0; s < 4; ++s) { gr[s] = 0.f; gi[s] = 0.f; }
        float cr = 1.f, ci = 0.f;
        #pragma unroll 4
        for (int k2 = 0; k2 < 32; ++k2) {
            int k = k1 + 16 * k2;
            #pragma unroll
            for (int s = 0; s < 4; ++s) {
                float2 z = Zp[s * 512 + k];
                gr[s] += z.x * cr - z.y * ci;
                gi[s] += z.x * ci + z.y * cr;
            }
            float ncr = cr * stepc - ci * steps;
            ci = cr * steps + ci * stepc;
            cr = ncr;
        }
        #pragma unroll
        for (int s = 0; s < 4; ++s)
            Gl[(k1 * 32 + tau) * 5 + s] = make_float2(gr[s], gi[s]);
    }
    __syncthreads();

    // stage 2: y_pair[t] = sum_{k1} G[k1][t&31] e^{+i 2pi k1 t/512}; Re->frame a, Im->frame b
    int t = tid;
    int tau = t & 31;
    float sa2, ca2;
    sincosf((float)t * (float)(2.0 * M_PI / 512.0), &sa2, &ca2);
    float stepc = ca2, steps = sa2;
    float accr[4], acci[4];
    #pragma unroll
    for (int s = 0; s < 4; ++s) { accr[s] = 0.f; acci[s] = 0.f; }
    float cr = 1.f, ci = 0.f;
    #pragma unroll 4
    for (int k1 = 0; k1 < 16; ++k1) {
        #pragma unroll
        for (int s = 0; s < 4; ++s) {
            float2 gv = Gl[(k1 * 32 + tau) * 5 + s];
            accr[s] += gv.x * cr - gv.y * ci;
            acci[s] += gv.x * ci + gv.y * cr;
        }
        float ncr = cr * stepc - ci * steps;
        ci = cr * steps + ci * stepc;
        cr = ncr;
    }
    float wv = tw[t] * (1.f / 512.f);
    #pragma unroll
    for (int s = 0; s < 4; ++s) {
        int ma = m0 + 2 * s, mb_ = ma + 1;
        if (ma < NF)  atomicAdd(&y[(size_t)b * YLEN + ma * HOP + t], accr[s] * wv);
        if (mb_ < NF) atomicAdd(&y[(size_t)b * YLEN + mb_ * HOP + t], acci[s] * wv);
    }
}

// ---------------- normalize by window sum, trim padding ----------------
__global__ __launch_bounds__(256) void k_out(const float* __restrict__ y,
                                             const float* __restrict__ tw,
                                             float* __restrict__ out) {
    int i = blockIdx.x * blockDim.x + threadIdx.x;
    if (i >= BATCH * TLEN) return;
    int b = i / TLEN;
    int t = i % TLEN;
    int p = t + PADW;
    float wsum = 0.f;
    int m0 = p >> 7;
    #pragma unroll
    for (int dm = 0; dm < 4; ++dm) {
        int mm = m0 - dm;
        if (mm >= 0 && mm < NF) {
            float wv = tw[p - mm * HOP];
            wsum += wv * wv;
        }
    }
    out[i] = y[(size_t)b * YLEN + p] / fmaxf(wsum, 1e-10f);
}

extern "C" void kernel_launch(void* const* d_in, const int* in_sizes, int n_in,
                              void* d_out, int out_size, void* d_ws, size_t ws_size,
                              hipStream_t stream) {
    const float* x  = (const float*)d_in[0];
    const float* w1 = (const float*)d_in[1];
    const float* b1 = (const float*)d_in[2];
    const float* w2 = (const float*)d_in[3];
    const float* b2 = (const float*)d_in[4];

    float* ws = (float*)d_ws;
    size_t off = 0;
    float*  tw   = ws + off; off += 512;
    float2* X    = (float2*)(ws + off); off += (size_t)BATCH * FP * NF * CH * 2;
    float*  feat = ws + off; off += (size_t)BATCH * NF * FP;     // feat+h region reused as `part`
    float*  h    = ws + off; off += (size_t)BATCH * NF * HID;
    float*  mo   = ws + off; off += (size_t)BATCH * NF * HID;
    float2* wc   = (float2*)(ws + off); off += (size_t)BATCH * FP * CH * 2;
    float2* Xe   = (float2*)(ws + off); off += (size_t)BATCH * NF * FP * 2;
    float*  y    = ws + off; off += (size_t)BATCH * YLEN;

    float4* part = (float4*)feat;   // 8*32*5*512*16B = 10.5 MB <= feat+h (12.3 MB), dead by cov time

    hipMemsetAsync(y, 0, (size_t)BATCH * YLEN * sizeof(float), stream);

    k_tables<<<2, 256, 0, stream>>>(tw);
    k_stft<<<BATCH * CH * NGRP, 256, 0, stream>>>(x, tw, X, feat);
    k_mlp1<<<(BATCH * NF / 8) * 2, 256, 0, stream>>>(feat, w1, b1, h);
    k_mlp2<<<(BATCH * NF / 8) * 2, 256, 0, stream>>>(h, w2, b2, mo);
    k_cov_part<<<BATCH * 32 * NCK, 512, 0, stream>>>(X, mo, part);
    k_cov_solve2<<<BATCH * 32, 512, 0, stream>>>(part, wc);
    k_beamform<<<BATCH * NF, 256, 0, stream>>>(X, wc, Xe);
    k_istft<<<BATCH * NGRP, 512, 0, stream>>>(Xe, tw, y);
    k_out<<<(BATCH * TLEN + 255) / 256, 256, 0, stream>>>(y, tw, (float*)d_out);
}

// Round 5
// 248.935 us; speedup vs baseline: 7.0689x; 1.1802x over previous
//
#include <hip/hip_runtime.h>
#include <math.h>

#define NFFT 512
#define HOP  128
#define PADW 256
#define TLEN 64000
#define NF   501
#define FP   256
#define CH   8
#define BATCH 8
#define HID  512
#define YLEN 64512  // NFFT + HOP*(NF-1)
#define FPB  8      // frames per block (stft/istft)
#define NGRP 63     // ceil(NF/FPB)
#define CNCK 8      // cov n-chunks
#define CCK  63     // ceil(NF/CNCK)

// Y LDS index for stft: [t1][j][fr], j rotated by 2*t1, row padded to 9 float2
__device__ __forceinline__ int Yidx(int t1, int j, int fr) {
    return (t1 * 32 + ((j + 2 * t1) & 31)) * 9 + fr;
}

// ---------------- tables: hann window ----------------
__global__ void k_tables(float* tw) {
    int j = threadIdx.x + blockIdx.x * blockDim.x;
    if (j < 512) {
        float ang = (float)(2.0 * M_PI * (double)j / 512.0);
        tw[j] = 0.5f - 0.5f * cosf(ang);
    }
}

// ---------------- STFT: two-stage Cooley-Tukey (512 = 16 x 32), 8 frames/block ----------------
__global__ __launch_bounds__(256) void k_stft(const float* __restrict__ x,
                                              const float* __restrict__ tw,
                                              float2* __restrict__ X,
                                              float* __restrict__ feat) {
    __shared__ float sT[512][8];          // [t][frame]
    __shared__ float2 Yl[16 * 32 * 9];    // inner DFT-32 results
    int blk = blockIdx.x;
    int g = blk % NGRP;
    int bc = blk / NGRP;
    int c = bc % CH, b = bc / CH;
    int m0 = g * FPB;
    int tid = threadIdx.x;
    const float* xp = x + (size_t)(b * CH + c) * TLEN;

    for (int i = tid; i < FPB * 512; i += 256) {
        int t = i >> 3, fr = i & 7;
        int j = (m0 + fr) * HOP + t - PADW;   // reflect pad
        if (j < 0) j = -j;
        if (j >= TLEN) j = 2 * (TLEN - 1) - j;
        sT[t][fr] = xp[j] * tw[t];
    }
    __syncthreads();

    // stage B: inner DFT-32
    {
        int jj = tid >> 3, q = tid & 7;
        float sj, cj;
        sincosf((float)jj * (float)(2.0 * M_PI / 32.0), &sj, &cj);
        float stepc = cj, steps = -sj;        // e^{-i 2pi j/32}
        float y0r[8], y0i[8], y1r[8], y1i[8];
        #pragma unroll
        for (int fr = 0; fr < 8; ++fr) { y0r[fr] = 0.f; y0i[fr] = 0.f; y1r[fr] = 0.f; y1i[fr] = 0.f; }
        float cr = 1.f, ci = 0.f;
        #pragma unroll 4
        for (int t2 = 0; t2 < 32; ++t2) {
            const float4 a0 = *(const float4*)&sT[q + 16 * t2][0];
            const float4 a1 = *(const float4*)&sT[q + 16 * t2][4];
            const float4 b0 = *(const float4*)&sT[q + 8 + 16 * t2][0];
            const float4 b1 = *(const float4*)&sT[q + 8 + 16 * t2][4];
            float av[8] = {a0.x, a0.y, a0.z, a0.w, a1.x, a1.y, a1.z, a1.w};
            float bv[8] = {b0.x, b0.y, b0.z, b0.w, b1.x, b1.y, b1.z, b1.w};
            #pragma unroll
            for (int fr = 0; fr < 8; ++fr) {
                y0r[fr] += av[fr] * cr; y0i[fr] += av[fr] * ci;
                y1r[fr] += bv[fr] * cr; y1i[fr] += bv[fr] * ci;
            }
            float ncr = cr * stepc - ci * steps;
            ci = cr * steps + ci * stepc;
            cr = ncr;
        }
        #pragma unroll
        for (int fr = 0; fr < 8; ++fr) {
            Yl[Yidx(q, jj, fr)]     = make_float2(y0r[fr], y0i[fr]);
            Yl[Yidx(q + 8, jj, fr)] = make_float2(y1r[fr], y1i[fr]);
        }
    }
    __syncthreads();

    // stage C: combine
    int k = tid + 1;
    int j = k & 31;
    float sk, ck;
    sincosf((float)k * (float)(2.0 * M_PI / 512.0), &sk, &ck);
    float stepc = ck, steps = -sk;            // e^{-i 2pi k/512}
    float xr_[8], xi_[8];
    #pragma unroll
    for (int fr = 0; fr < 8; ++fr) { xr_[fr] = 0.f; xi_[fr] = 0.f; }
    float cr = 1.f, ci = 0.f;
    #pragma unroll 4
    for (int t1 = 0; t1 < 16; ++t1) {
        #pragma unroll
        for (int fr = 0; fr < 8; ++fr) {
            float2 yv = Yl[Yidx(t1, j, fr)];
            xr_[fr] += yv.x * cr - yv.y * ci;
            xi_[fr] += yv.x * ci + yv.y * cr;
        }
        float ncr = cr * stepc - ci * steps;
        ci = cr * steps + ci * stepc;
        cr = ncr;
    }
    int fbin = k - 1;
    #pragma unroll
    for (int fr = 0; fr < 8; ++fr) {
        int m = m0 + fr;
        if (m < NF) {
            X[((size_t)(b * NF + m) * CH + c) * FP + fbin] = make_float2(xr_[fr], xi_[fr]);
            if (c == 0)
                feat[((size_t)b * NF + m) * FP + fbin] = sqrtf(xr_[fr] * xr_[fr] + xi_[fr] * xi_[fr]);
        }
    }
}

// ---------------- MLP layer 1: activations via uniform (scalar) loads, no LDS ----------------
__global__ __launch_bounds__(512) void k_mlp1(const float* __restrict__ feat,
                                              const float* __restrict__ w1,
                                              const float* __restrict__ b1,
                                              float* __restrict__ h) {
    int row0 = blockIdx.x * 8;          // 501 blocks
    int j = threadIdx.x;                // 0..511
    const float* fr0 = feat + (size_t)row0 * FP;
    float bj = b1[j];
    float acc[8];
    #pragma unroll
    for (int r = 0; r < 8; ++r) acc[r] = bj;
    #pragma unroll 4
    for (int f = 0; f < FP; ++f) {
        float wv = w1[(size_t)f * HID + j];
        #pragma unroll
        for (int r = 0; r < 8; ++r) acc[r] += fr0[r * FP + f] * wv;   // uniform -> s_load
    }
    #pragma unroll
    for (int r = 0; r < 8; ++r)
        h[(size_t)(row0 + r) * HID + j] = fmaxf(acc[r], 0.f);
}

// ---------------- MLP layer 2 ----------------
__global__ __launch_bounds__(512) void k_mlp2(const float* __restrict__ h,
                                              const float* __restrict__ w2,
                                              const float* __restrict__ b2,
                                              float* __restrict__ mo) {
    int row0 = blockIdx.x * 8;
    int j = threadIdx.x;
    const float* hr0 = h + (size_t)row0 * HID;
    float bj = b2[j];
    float acc[8];
    #pragma unroll
    for (int r = 0; r < 8; ++r) acc[r] = bj;
    #pragma unroll 4
    for (int f = 0; f < HID; ++f) {
        float wv = w2[(size_t)f * HID + j];
        #pragma unroll
        for (int r = 0; r < 8; ++r) acc[r] += hr0[r * HID + f] * wv;  // uniform -> s_load
    }
    #pragma unroll
    for (int r = 0; r < 8; ++r)
        mo[(size_t)(row0 + r) * HID + j] = 1.f / (1.f + expf(-acc[r]));
}

// ---------------- covariance partials: block = (b, ftile64, nchunk), LDS-staged ----------------
// part layout: [nc][b][f][72] float2 : slots 0..63 = R[c][d], 64..71 = rhs[c]
__global__ __launch_bounds__(512) void k_cov(const float2* __restrict__ X,
                                             const float* __restrict__ mo,
                                             float2* __restrict__ part) {
    int blk = blockIdx.x;               // ((b*4 + ftile)*8 + nc)
    int nc = blk & 7;
    int ftile = (blk >> 3) & 3;
    int b = blk >> 5;
    int tid = threadIdx.x;
    int c = tid >> 6;                   // wave index = channel
    int ft = tid & 63;
    int f = ftile * 64 + ft;
    int n0 = nc * CCK;
    int n1 = n0 + CCK; if (n1 > NF) n1 = NF;

    __shared__ float2 vbuf[2][CH][64];

    float ar[8], ai[8];
    #pragma unroll
    for (int d = 0; d < 8; ++d) { ar[d] = 0.f; ai[d] = 0.f; }
    float rr = 0.f, ri = 0.f;

    const float2* Xb = X + (size_t)b * NF * CH * FP;
    const float* mb = mo + (size_t)b * NF * HID;

    vbuf[0][c][ft] = Xb[(size_t)(n0 * CH + c) * FP + f];
    __syncthreads();
    int cur = 0;
    for (int n = n0; n < n1; ++n) {
        float2 nx;
        bool more = (n + 1 < n1);
        if (more) nx = Xb[(size_t)((n + 1) * CH + c) * FP + f];
        float mt = mb[(size_t)n * HID + f];
        float mn = mb[(size_t)n * HID + FP + f];
        float w = mt + mn;
        float2 xc = vbuf[cur][c][ft];
        #pragma unroll
        for (int d = 0; d < 8; ++d) {
            float2 xd = vbuf[cur][d][ft];
            float pr = xc.x * xd.x + xc.y * xd.y;   // xc * conj(xd)
            float pi = xc.y * xd.x - xc.x * xd.y;
            ar[d] += w * pr; ai[d] += w * pi;
            if (d == 0) { rr += mt * pr; ri += mt * pi; }
        }
        if (more) vbuf[cur ^ 1][c][ft] = nx;
        __syncthreads();
        cur ^= 1;
    }
    float2* pp = part + (((size_t)nc * BATCH + b) * FP + f) * 72;
    #pragma unroll
    for (int d = 0; d < 8; ++d)
        pp[c * 8 + d] = make_float2(ar[d], ai[d]);
    pp[64 + c] = make_float2(rr, ri);
}

// ---------------- reduce partials + 8x8 complex solve: block = (b, fgroup8) ----------------
__global__ __launch_bounds__(512) void k_cov_solve2(const float2* __restrict__ part,
                                                    float2* __restrict__ wc) {
    int blk = blockIdx.x;          // b*32 + fg
    int fg = blk & 31;
    int b = blk >> 5;
    int tid = threadIdx.x;
    int c = tid >> 6, d = (tid >> 3) & 7, fl = tid & 7;
    int f = fg * 8 + fl;
    float ar = 0.f, ai = 0.f, rr = 0.f, ri = 0.f;
    const float2* pb = part + ((size_t)b * FP + f) * 72;
    #pragma unroll
    for (int nc = 0; nc < CNCK; ++nc) {
        const float2* p = pb + (size_t)nc * BATCH * FP * 72;
        float2 v = p[c * 8 + d];
        ar += v.x; ai += v.y;
        if (d == 0) { float2 u = p[64 + c]; rr += u.x; ri += u.y; }
    }
    __shared__ float2 Am[8][73];
    __shared__ float2 rh[8][8];
    __shared__ float2 sl[8][9];
    Am[fl][c * 9 + d] = make_float2(ar, ai);
    if (d == 0) rh[fl][c] = make_float2(rr, ri);
    __syncthreads();
    if (tid < 8) {
        int ln = tid;
        float2* A = Am[ln];
        float2* r = rh[ln];
        float2* sol = sl[ln];
        for (int kk = 0; kk < 8; ++kk) {
            float2 pp = A[kk * 9 + kk];
            float ip = 1.f / (pp.x * pp.x + pp.y * pp.y);
            float invr = pp.x * ip, invi = -pp.y * ip;
            for (int i = kk + 1; i < 8; ++i) {
                float2 aik = A[i * 9 + kk];
                float fr2 = aik.x * invr - aik.y * invi;
                float fi2 = aik.x * invi + aik.y * invr;
                for (int jj = kk; jj < 8; ++jj) {
                    float2 ak = A[kk * 9 + jj];
                    A[i * 9 + jj].x -= fr2 * ak.x - fi2 * ak.y;
                    A[i * 9 + jj].y -= fr2 * ak.y + fi2 * ak.x;
                }
                r[i].x -= fr2 * r[kk].x - fi2 * r[kk].y;
                r[i].y -= fr2 * r[kk].y + fi2 * r[kk].x;
            }
        }
        for (int kk = 7; kk >= 0; --kk) {
            float sr = r[kk].x, si = r[kk].y;
            for (int jj = kk + 1; jj < 8; ++jj) {
                float2 ak = A[kk * 9 + jj];
                float2 xj = sol[jj];
                sr -= ak.x * xj.x - ak.y * xj.y;
                si -= ak.x * xj.y + ak.y * xj.x;
            }
            float2 pp = A[kk * 9 + kk];
            float ip = 1.f / (pp.x * pp.x + pp.y * pp.y);
            sol[kk].x = (sr * pp.x + si * pp.y) * ip;
            sol[kk].y = (si * pp.x - sr * pp.y) * ip;
        }
        for (int cc = 0; cc < 8; ++cc)   // wc layout [b][c][f], store conj
            wc[((size_t)b * CH + cc) * FP + fg * 8 + ln] = make_float2(sol[cc].x, -sol[cc].y);
    }
}

// ---------------- beamform ----------------
__global__ __launch_bounds__(256) void k_beamform(const float2* __restrict__ X,
                                                  const float2* __restrict__ wc,
                                                  float2* __restrict__ Xe) {
    int blk = blockIdx.x;
    int n = blk % NF, b = blk / NF;
    int f = threadIdx.x;
    float er = 0.f, ei = 0.f;
    #pragma unroll
    for (int c = 0; c < 8; ++c) {
        float2 xv = X[((size_t)(b * NF + n) * CH + c) * FP + f];
        float2 wv = wc[((size_t)b * CH + c) * FP + f];
        er += xv.x * wv.x - xv.y * wv.y;
        ei += xv.x * wv.y + xv.y * wv.x;
    }
    Xe[((size_t)b * NF + n) * FP + f] = make_float2(er, ei);
}

// ---------------- ISTFT: real-pair + two-stage (512 = 16 x 32) iDFT ----------------
__global__ __launch_bounds__(512) void k_istft(const float2* __restrict__ Xe,
                                               const float* __restrict__ tw,
                                               float* __restrict__ y) {
    __shared__ float2 Zp[4 * 512];          // [sig][k] Hermitian-combined spectra
    __shared__ float2 Gl[16 * 32 * 5];      // [k1][tau][sig] pad 5
    int blk = blockIdx.x;
    int g = blk % NGRP, b = blk / NGRP;
    int m0 = g * FPB;
    int tid = threadIdx.x;

    if (tid < 4) Zp[tid * 512] = make_float2(0.f, 0.f);   // k = 0 (DC dropped)
    for (int i = tid; i < 4 * 256; i += 512) {
        int sig = i >> 8, kp = i & 255;     // bin kp -> k = kp+1
        int ma = m0 + 2 * sig, mb_ = ma + 1;
        float2 Xa = (ma < NF) ? Xe[((size_t)b * NF + ma) * FP + kp] : make_float2(0.f, 0.f);
        float2 Xb = (mb_ < NF) ? Xe[((size_t)b * NF + mb_) * FP + kp] : make_float2(0.f, 0.f);
        int k = kp + 1;
        if (k == 256) {
            Zp[sig * 512 + 256] = make_float2(Xa.x, Xb.x);   // Nyquist: real parts only
        } else {
            Zp[sig * 512 + k]       = make_float2(Xa.x - Xb.y, Xa.y + Xb.x);
            Zp[sig * 512 + 512 - k] = make_float2(Xa.x + Xb.y, Xb.x - Xa.y);
        }
    }
    __syncthreads();

    // stage 1
    {
        int k1 = tid >> 5, tau = tid & 31;
        float sa, ca;
        sincosf((float)tau * (float)(2.0 * M_PI / 32.0), &sa, &ca);
        float stepc = ca, steps = sa;
        float gr[4], gi[4];
        #pragma unroll
        for (int s = 0; s < 4; ++s) { gr[s] = 0.f; gi[s] = 0.f; }
        float cr = 1.f, ci = 0.f;
        #pragma unroll 4
        for (int k2 = 0; k2 < 32; ++k2) {
            int k = k1 + 16 * k2;
            #pragma unroll
            for (int s = 0; s < 4; ++s) {
                float2 z = Zp[s * 512 + k];
                gr[s] += z.x * cr - z.y * ci;
                gi[s] += z.x * ci + z.y * cr;
            }
            float ncr = cr * stepc - ci * steps;
            ci = cr * steps + ci * stepc;
            cr = ncr;
        }
        #pragma unroll
        for (int s = 0; s < 4; ++s)
            Gl[(k1 * 32 + tau) * 5 + s] = make_float2(gr[s], gi[s]);
    }
    __syncthreads();

    // stage 2
    int t = tid;
    int tau = t & 31;
    float sa2, ca2;
    sincosf((float)t * (float)(2.0 * M_PI / 512.0), &sa2, &ca2);
    float stepc = ca2, steps = sa2;
    float accr[4], acci[4];
    #pragma unroll
    for (int s = 0; s < 4; ++s) { accr[s] = 0.f; acci[s] = 0.f; }
    float cr = 1.f, ci = 0.f;
    #pragma unroll 4
    for (int k1 = 0; k1 < 16; ++k1) {
        #pragma unroll
        for (int s = 0; s < 4; ++s) {
            float2 gv = Gl[(k1 * 32 + tau) * 5 + s];
            accr[s] += gv.x * cr - gv.y * ci;
            acci[s] += gv.x * ci + gv.y * cr;
        }
        float ncr = cr * stepc - ci * steps;
        ci = cr * steps + ci * stepc;
        cr = ncr;
    }
    float wv = tw[t] * (1.f / 512.f);
    #pragma unroll
    for (int s = 0; s < 4; ++s) {
        int ma = m0 + 2 * s, mb_ = ma + 1;
        if (ma < NF)  atomicAdd(&y[(size_t)b * YLEN + ma * HOP + t], accr[s] * wv);
        if (mb_ < NF) atomicAdd(&y[(size_t)b * YLEN + mb_ * HOP + t], acci[s] * wv);
    }
}

// ---------------- normalize by window sum, trim padding ----------------
__global__ __launch_bounds__(256) void k_out(const float* __restrict__ y,
                                             const float* __restrict__ tw,
                                             float* __restrict__ out) {
    int i = blockIdx.x * blockDim.x + threadIdx.x;
    if (i >= BATCH * TLEN) return;
    int b = i / TLEN;
    int t = i % TLEN;
    int p = t + PADW;
    float wsum = 0.f;
    int m0 = p >> 7;
    #pragma unroll
    for (int dm = 0; dm < 4; ++dm) {
        int mm = m0 - dm;
        if (mm >= 0 && mm < NF) {
            float wv = tw[p - mm * HOP];
            wsum += wv * wv;
        }
    }
    out[i] = y[(size_t)b * YLEN + p] / fmaxf(wsum, 1e-10f);
}

extern "C" void kernel_launch(void* const* d_in, const int* in_sizes, int n_in,
                              void* d_out, int out_size, void* d_ws, size_t ws_size,
                              hipStream_t stream) {
    const float* x  = (const float*)d_in[0];
    const float* w1 = (const float*)d_in[1];
    const float* b1 = (const float*)d_in[2];
    const float* w2 = (const float*)d_in[3];
    const float* b2 = (const float*)d_in[4];

    float* ws = (float*)d_ws;
    size_t off = 0;
    float*  tw   = ws + off; off += 512;
    float2* X    = (float2*)(ws + off); off += (size_t)BATCH * FP * NF * CH * 2;
    float*  feat = ws + off; off += (size_t)BATCH * NF * FP;     // feat+h reused as `part`
    float*  h    = ws + off; off += (size_t)BATCH * NF * HID;
    float*  mo   = ws + off; off += (size_t)BATCH * NF * HID;
    float2* wc   = (float2*)(ws + off); off += (size_t)BATCH * FP * CH * 2;
    float2* Xe   = (float2*)(ws + off); off += (size_t)BATCH * NF * FP * 2;
    float*  y    = ws + off; off += (size_t)BATCH * YLEN;

    // part: [8][8][256][72] float2 = 9.44 MB <= feat+h (12.3 MB), both dead after mlp2
    float2* part = (float2*)feat;

    hipMemsetAsync(y, 0, (size_t)BATCH * YLEN * sizeof(float), stream);

    k_tables<<<2, 256, 0, stream>>>(tw);
    k_stft<<<BATCH * CH * NGRP, 256, 0, stream>>>(x, tw, X, feat);
    k_mlp1<<<BATCH * NF / 8, 512, 0, stream>>>(feat, w1, b1, h);
    k_mlp2<<<BATCH * NF / 8, 512, 0, stream>>>(h, w2, b2, mo);
    k_cov<<<BATCH * 4 * CNCK, 512, 0, stream>>>(X, mo, part);
    k_cov_solve2<<<BATCH * 32, 512, 0, stream>>>(part, wc);
    k_beamform<<<BATCH * NF, 256, 0, stream>>>(X, wc, Xe);
    k_istft<<<BATCH * NGRP, 512, 0, stream>>>(Xe, tw, y);
    k_out<<<(BATCH * TLEN + 255) / 256, 256, 0, stream>>>(y, tw, (float*)d_out);
}

// Round 6
// 228.312 us; speedup vs baseline: 7.7074x; 1.0903x over previous
//
#include <hip/hip_runtime.h>
#include <math.h>

#define NFFT 512
#define HOP  128
#define PADW 256
#define TLEN 64000
#define NF   501
#define NFP  504    // padded frame count for yfr rows
#define FP   256
#define CH   8
#define BATCH 8
#define HID  512
#define FPB  8      // frames per block (stft/istft)
#define NGRP 63     // ceil(NF/FPB)
#define CNCK 8      // cov n-chunks
#define CCK  63     // ceil(NF/CNCK)
#define NSTG 4      // cov frames staged per sync round

// Y LDS index for stft: [t1][j][fr], j rotated by 2*t1, row padded to 9 float2
__device__ __forceinline__ int Yidx(int t1, int j, int fr) {
    return (t1 * 32 + ((j + 2 * t1) & 31)) * 9 + fr;
}

// ---------------- tables: hann window (used by stft staging) ----------------
__global__ void k_tables(float* tw) {
    int j = threadIdx.x + blockIdx.x * blockDim.x;
    if (j < 512) {
        float ang = (float)(2.0 * M_PI * (double)j / 512.0);
        tw[j] = 0.5f - 0.5f * cosf(ang);
    }
}

// ---------------- STFT: two-stage Cooley-Tukey (512 = 16 x 32), 8 frames/block ----------------
__global__ __launch_bounds__(256) void k_stft(const float* __restrict__ x,
                                              const float* __restrict__ tw,
                                              float2* __restrict__ X,
                                              float* __restrict__ feat) {
    __shared__ float sT[512][8];          // [t][frame]
    __shared__ float2 Yl[16 * 32 * 9];    // inner DFT-32 results
    int blk = blockIdx.x;
    int g = blk % NGRP;
    int bc = blk / NGRP;
    int c = bc % CH, b = bc / CH;
    int m0 = g * FPB;
    int tid = threadIdx.x;
    const float* xp = x + (size_t)(b * CH + c) * TLEN;

    for (int i = tid; i < FPB * 512; i += 256) {
        int t = i >> 3, fr = i & 7;
        int j = (m0 + fr) * HOP + t - PADW;   // reflect pad
        if (j < 0) j = -j;
        if (j >= TLEN) j = 2 * (TLEN - 1) - j;
        sT[t][fr] = xp[j] * tw[t];
    }
    __syncthreads();

    // stage B: inner DFT-32
    {
        int jj = tid >> 3, q = tid & 7;
        float sj, cj;
        sincosf((float)jj * (float)(2.0 * M_PI / 32.0), &sj, &cj);
        float stepc = cj, steps = -sj;        // e^{-i 2pi j/32}
        float y0r[8], y0i[8], y1r[8], y1i[8];
        #pragma unroll
        for (int fr = 0; fr < 8; ++fr) { y0r[fr] = 0.f; y0i[fr] = 0.f; y1r[fr] = 0.f; y1i[fr] = 0.f; }
        float cr = 1.f, ci = 0.f;
        #pragma unroll 4
        for (int t2 = 0; t2 < 32; ++t2) {
            const float4 a0 = *(const float4*)&sT[q + 16 * t2][0];
            const float4 a1 = *(const float4*)&sT[q + 16 * t2][4];
            const float4 b0 = *(const float4*)&sT[q + 8 + 16 * t2][0];
            const float4 b1 = *(const float4*)&sT[q + 8 + 16 * t2][4];
            float av[8] = {a0.x, a0.y, a0.z, a0.w, a1.x, a1.y, a1.z, a1.w};
            float bv[8] = {b0.x, b0.y, b0.z, b0.w, b1.x, b1.y, b1.z, b1.w};
            #pragma unroll
            for (int fr = 0; fr < 8; ++fr) {
                y0r[fr] += av[fr] * cr; y0i[fr] += av[fr] * ci;
                y1r[fr] += bv[fr] * cr; y1i[fr] += bv[fr] * ci;
            }
            float ncr = cr * stepc - ci * steps;
            ci = cr * steps + ci * stepc;
            cr = ncr;
        }
        #pragma unroll
        for (int fr = 0; fr < 8; ++fr) {
            Yl[Yidx(q, jj, fr)]     = make_float2(y0r[fr], y0i[fr]);
            Yl[Yidx(q + 8, jj, fr)] = make_float2(y1r[fr], y1i[fr]);
        }
    }
    __syncthreads();

    // stage C: combine
    int k = tid + 1;
    int j = k & 31;
    float sk, ck;
    sincosf((float)k * (float)(2.0 * M_PI / 512.0), &sk, &ck);
    float stepc = ck, steps = -sk;            // e^{-i 2pi k/512}
    float xr_[8], xi_[8];
    #pragma unroll
    for (int fr = 0; fr < 8; ++fr) { xr_[fr] = 0.f; xi_[fr] = 0.f; }
    float cr = 1.f, ci = 0.f;
    #pragma unroll 4
    for (int t1 = 0; t1 < 16; ++t1) {
        #pragma unroll
        for (int fr = 0; fr < 8; ++fr) {
            float2 yv = Yl[Yidx(t1, j, fr)];
            xr_[fr] += yv.x * cr - yv.y * ci;
            xi_[fr] += yv.x * ci + yv.y * cr;
        }
        float ncr = cr * stepc - ci * steps;
        ci = cr * steps + ci * stepc;
        cr = ncr;
    }
    int fbin = k - 1;
    #pragma unroll
    for (int fr = 0; fr < 8; ++fr) {
        int m = m0 + fr;
        if (m < NF) {
            X[((size_t)(b * NF + m) * CH + c) * FP + fbin] = make_float2(xr_[fr], xi_[fr]);
            if (c == 0)
                feat[((size_t)b * NF + m) * FP + fbin] = sqrtf(xr_[fr] * xr_[fr] + xi_[fr] * xi_[fr]);
        }
    }
}

// ---------------- MLP layer 1: activations via uniform (scalar) loads ----------------
__global__ __launch_bounds__(512) void k_mlp1(const float* __restrict__ feat,
                                              const float* __restrict__ w1,
                                              const float* __restrict__ b1,
                                              float* __restrict__ h) {
    int row0 = blockIdx.x * 8;
    int j = threadIdx.x;
    const float* fr0 = feat + (size_t)row0 * FP;
    float bj = b1[j];
    float acc[8];
    #pragma unroll
    for (int r = 0; r < 8; ++r) acc[r] = bj;
    #pragma unroll 4
    for (int f = 0; f < FP; ++f) {
        float wv = w1[(size_t)f * HID + j];
        #pragma unroll
        for (int r = 0; r < 8; ++r) acc[r] += fr0[r * FP + f] * wv;
    }
    #pragma unroll
    for (int r = 0; r < 8; ++r)
        h[(size_t)(row0 + r) * HID + j] = fmaxf(acc[r], 0.f);
}

// ---------------- MLP layer 2 ----------------
__global__ __launch_bounds__(512) void k_mlp2(const float* __restrict__ h,
                                              const float* __restrict__ w2,
                                              const float* __restrict__ b2,
                                              float* __restrict__ mo) {
    int row0 = blockIdx.x * 8;
    int j = threadIdx.x;
    const float* hr0 = h + (size_t)row0 * HID;
    float bj = b2[j];
    float acc[8];
    #pragma unroll
    for (int r = 0; r < 8; ++r) acc[r] = bj;
    #pragma unroll 4
    for (int f = 0; f < HID; ++f) {
        float wv = w2[(size_t)f * HID + j];
        #pragma unroll
        for (int r = 0; r < 8; ++r) acc[r] += hr0[r * HID + f] * wv;
    }
    #pragma unroll
    for (int r = 0; r < 8; ++r)
        mo[(size_t)(row0 + r) * HID + j] = 1.f / (1.f + expf(-acc[r]));
}

// ---------------- covariance partials: 4 frames staged per sync round ----------------
// part layout: [nc][b][f][72] float2 : slots 0..63 = R[c][d], 64..71 = rhs[c]
__global__ __launch_bounds__(512) void k_cov(const float2* __restrict__ X,
                                             const float* __restrict__ mo,
                                             float2* __restrict__ part) {
    int blk = blockIdx.x;               // ((b*4 + ftile)*8 + nc)
    int nc = blk & 7;
    int ftile = (blk >> 3) & 3;
    int b = blk >> 5;
    int tid = threadIdx.x;
    int c = tid >> 6;
    int ft = tid & 63;
    int f = ftile * 64 + ft;
    int n0 = nc * CCK;
    int n1 = n0 + CCK; if (n1 > NF) n1 = NF;

    __shared__ float2 vbuf[2][NSTG][CH][64];   // 32 KB

    float ar[8], ai[8];
    #pragma unroll
    for (int d = 0; d < 8; ++d) { ar[d] = 0.f; ai[d] = 0.f; }
    float rr = 0.f, ri = 0.f;

    const float2* Xb = X + (size_t)b * NF * CH * FP;
    const float* mb = mo + (size_t)b * NF * HID;

    #pragma unroll
    for (int r = 0; r < NSTG; ++r) {
        int n = n0 + r;
        if (n < n1) vbuf[0][r][c][ft] = Xb[(size_t)(n * CH + c) * FP + f];
    }
    __syncthreads();
    int cur = 0;
    for (int nb = n0; nb < n1; nb += NSTG) {
        int nbn = nb + NSTG;
        float2 nx[NSTG];
        #pragma unroll
        for (int r = 0; r < NSTG; ++r) {
            int n = nbn + r;
            if (n < n1) nx[r] = Xb[(size_t)(n * CH + c) * FP + f];
        }
        float mts[NSTG], mns[NSTG];
        #pragma unroll
        for (int r = 0; r < NSTG; ++r) {
            int n = nb + r;
            if (n < n1) {
                mts[r] = mb[(size_t)n * HID + f];
                mns[r] = mb[(size_t)n * HID + FP + f];
            }
        }
        #pragma unroll
        for (int r = 0; r < NSTG; ++r) {
            int n = nb + r;
            if (n < n1) {
                float mt = mts[r], mn = mns[r];
                float w = mt + mn;
                float2 xc = vbuf[cur][r][c][ft];
                #pragma unroll
                for (int d = 0; d < 8; ++d) {
                    float2 xd = vbuf[cur][r][d][ft];
                    float pr = xc.x * xd.x + xc.y * xd.y;   // xc * conj(xd)
                    float pi = xc.y * xd.x - xc.x * xd.y;
                    ar[d] += w * pr; ai[d] += w * pi;
                    if (d == 0) { rr += mt * pr; ri += mt * pi; }
                }
            }
        }
        if (nbn < n1) {
            #pragma unroll
            for (int r = 0; r < NSTG; ++r) {
                int n = nbn + r;
                if (n < n1) vbuf[cur ^ 1][r][c][ft] = nx[r];
            }
        }
        __syncthreads();
        cur ^= 1;
    }
    float2* pp = part + (((size_t)nc * BATCH + b) * FP + f) * 72;
    #pragma unroll
    for (int d = 0; d < 8; ++d)
        pp[c * 8 + d] = make_float2(ar[d], ai[d]);
    pp[64 + c] = make_float2(rr, ri);
}

// ---------------- reduce partials + 8x8 complex solve: block = (b, fgroup8) ----------------
__global__ __launch_bounds__(512) void k_cov_solve2(const float2* __restrict__ part,
                                                    float2* __restrict__ wc) {
    int blk = blockIdx.x;          // b*32 + fg
    int fg = blk & 31;
    int b = blk >> 5;
    int tid = threadIdx.x;
    int c = tid >> 6, d = (tid >> 3) & 7, fl = tid & 7;
    int f = fg * 8 + fl;
    float ar = 0.f, ai = 0.f, rr = 0.f, ri = 0.f;
    const float2* pb = part + ((size_t)b * FP + f) * 72;
    #pragma unroll
    for (int nc = 0; nc < CNCK; ++nc) {
        const float2* p = pb + (size_t)nc * BATCH * FP * 72;
        float2 v = p[c * 8 + d];
        ar += v.x; ai += v.y;
        if (d == 0) { float2 u = p[64 + c]; rr += u.x; ri += u.y; }
    }
    __shared__ float2 Am[8][73];
    __shared__ float2 rh[8][8];
    __shared__ float2 sl[8][9];
    Am[fl][c * 9 + d] = make_float2(ar, ai);
    if (d == 0) rh[fl][c] = make_float2(rr, ri);
    __syncthreads();
    if (tid < 8) {
        int ln = tid;
        float2* A = Am[ln];
        float2* r = rh[ln];
        float2* sol = sl[ln];
        for (int kk = 0; kk < 8; ++kk) {
            float2 pp = A[kk * 9 + kk];
            float ip = 1.f / (pp.x * pp.x + pp.y * pp.y);
            float invr = pp.x * ip, invi = -pp.y * ip;
            for (int i = kk + 1; i < 8; ++i) {
                float2 aik = A[i * 9 + kk];
                float fr2 = aik.x * invr - aik.y * invi;
                float fi2 = aik.x * invi + aik.y * invr;
                for (int jj = kk; jj < 8; ++jj) {
                    float2 ak = A[kk * 9 + jj];
                    A[i * 9 + jj].x -= fr2 * ak.x - fi2 * ak.y;
                    A[i * 9 + jj].y -= fr2 * ak.y + fi2 * ak.x;
                }
                r[i].x -= fr2 * r[kk].x - fi2 * r[kk].y;
                r[i].y -= fr2 * r[kk].y + fi2 * r[kk].x;
            }
        }
        for (int kk = 7; kk >= 0; --kk) {
            float sr = r[kk].x, si = r[kk].y;
            for (int jj = kk + 1; jj < 8; ++jj) {
                float2 ak = A[kk * 9 + jj];
                float2 xj = sol[jj];
                sr -= ak.x * xj.x - ak.y * xj.y;
                si -= ak.x * xj.y + ak.y * xj.x;
            }
            float2 pp = A[kk * 9 + kk];
            float ip = 1.f / (pp.x * pp.x + pp.y * pp.y);
            sol[kk].x = (sr * pp.x + si * pp.y) * ip;
            sol[kk].y = (si * pp.x - sr * pp.y) * ip;
        }
        for (int cc = 0; cc < 8; ++cc)   // wc layout [b][c][f], store conj
            wc[((size_t)b * CH + cc) * FP + fg * 8 + ln] = make_float2(sol[cc].x, -sol[cc].y);
    }
}

// ---------------- fused beamform + ISTFT: per-frame windowed iDFT rows, no atomics ----------------
__global__ __launch_bounds__(512) void k_istft_bf(const float2* __restrict__ X,
                                                  const float2* __restrict__ wc,
                                                  float* __restrict__ yfr) {
    __shared__ float2 Zp[4 * 512];          // [sig][k] Hermitian-combined spectra
    __shared__ float2 Gl[16 * 32 * 5];      // [k1][tau][sig] pad 5
    int blk = blockIdx.x;
    int g = blk % NGRP, b = blk / NGRP;
    int m0 = g * FPB;
    int tid = threadIdx.x;

    if (tid < 4) Zp[tid * 512] = make_float2(0.f, 0.f);   // k = 0 (DC dropped)
    const float2* Xb0 = X + (size_t)b * NF * CH * FP;
    const float2* wcb = wc + (size_t)b * CH * FP;
    #pragma unroll
    for (int half = 0; half < 2; ++half) {
        int i = half * 512 + tid;
        int sig = i >> 8, kp = i & 255;     // bin kp -> k = kp+1
        int ma = m0 + 2 * sig, mb_ = ma + 1;
        float2 Xa = make_float2(0.f, 0.f), Xb = make_float2(0.f, 0.f);
        if (ma < NF) {
            #pragma unroll
            for (int c = 0; c < 8; ++c) {
                float2 xv = Xb0[(size_t)(ma * CH + c) * FP + kp];
                float2 wv = wcb[c * FP + kp];
                Xa.x += xv.x * wv.x - xv.y * wv.y;
                Xa.y += xv.x * wv.y + xv.y * wv.x;
            }
        }
        if (mb_ < NF) {
            #pragma unroll
            for (int c = 0; c < 8; ++c) {
                float2 xv = Xb0[(size_t)(mb_ * CH + c) * FP + kp];
                float2 wv = wcb[c * FP + kp];
                Xb.x += xv.x * wv.x - xv.y * wv.y;
                Xb.y += xv.x * wv.y + xv.y * wv.x;
            }
        }
        int k = kp + 1;
        if (k == 256) {
            Zp[sig * 512 + 256] = make_float2(Xa.x, Xb.x);   // Nyquist: real parts only
        } else {
            Zp[sig * 512 + k]       = make_float2(Xa.x - Xb.y, Xa.y + Xb.x);
            Zp[sig * 512 + 512 - k] = make_float2(Xa.x + Xb.y, Xb.x - Xa.y);
        }
    }
    __syncthreads();

    // stage 1: G[k1][tau] = sum_{k2} Zp[k1+16*k2] e^{+i 2pi k2 tau/32}
    {
        int k1 = tid >> 5, tau = tid & 31;
        float sa, ca;
        sincosf((float)tau * (float)(2.0 * M_PI / 32.0), &sa, &ca);
        float stepc = ca, steps = sa;
        float gr[4], gi[4];
        #pragma unroll
        for (int s = 0; s < 4; ++s) { gr[s] = 0.f; gi[s] = 0.f; }
        float cr = 1.f, ci = 0.f;
        #pragma unroll 4
        for (int k2 = 0; k2 < 32; ++k2) {
            int k = k1 + 16 * k2;
            #pragma unroll
            for (int s = 0; s < 4; ++s) {
                float2 z = Zp[s * 512 + k];
                gr[s] += z.x * cr - z.y * ci;
                gi[s] += z.x * ci + z.y * cr;
            }
            float ncr = cr * stepc - ci * steps;
            ci = cr * steps + ci * stepc;
            cr = ncr;
        }
        #pragma unroll
        for (int s = 0; s < 4; ++s)
            Gl[(k1 * 32 + tau) * 5 + s] = make_float2(gr[s], gi[s]);
    }
    __syncthreads();

    // stage 2: y_pair[t] = sum_{k1} G[k1][t&31] e^{+i 2pi k1 t/512}; Re->frame a, Im->frame b
    int t = tid;
    int tau = t & 31;
    float sa2, ca2;
    sincosf((float)t * (float)(2.0 * M_PI / 512.0), &sa2, &ca2);
    float stepc = ca2, steps = sa2;
    float accr[4], acci[4];
    #pragma unroll
    for (int s = 0; s < 4; ++s) { accr[s] = 0.f; acci[s] = 0.f; }
    float cr = 1.f, ci = 0.f;
    #pragma unroll 4
    for (int k1 = 0; k1 < 16; ++k1) {
        #pragma unroll
        for (int s = 0; s < 4; ++s) {
            float2 gv = Gl[(k1 * 32 + tau) * 5 + s];
            accr[s] += gv.x * cr - gv.y * ci;
            acci[s] += gv.x * ci + gv.y * cr;
        }
        float ncr = cr * stepc - ci * steps;
        ci = cr * steps + ci * stepc;
        cr = ncr;
    }
    float wv = (0.5f - 0.5f * ca2) * (1.f / 512.f);   // hann(t) / 512
    #pragma unroll
    for (int s = 0; s < 4; ++s) {
        int ma = m0 + 2 * s, mb_ = ma + 1;
        if (ma < NF)  yfr[((size_t)b * NFP + ma) * 512 + t] = accr[s] * wv;
        if (mb_ < NF) yfr[((size_t)b * NFP + mb_) * 512 + t] = acci[s] * wv;
    }
}

// ---------------- gather overlap-add + wsum normalize ----------------
__global__ __launch_bounds__(256) void k_out(const float* __restrict__ yfr,
                                             float* __restrict__ out) {
    int i = blockIdx.x * blockDim.x + threadIdx.x;
    if (i >= BATCH * TLEN) return;
    int b = i / TLEN;
    int t = i - b * TLEN;
    int p = t + PADW;
    int q = p & 127;
    int m0 = p >> 7;
    float sq, cq;
    sincosf((float)q * (float)(2.0 * M_PI / 512.0), &sq, &cq);
    // hann(q + 128*dm) via quarter-period phase shifts
    float w4[4] = {0.5f - 0.5f * cq, 0.5f + 0.5f * sq, 0.5f + 0.5f * cq, 0.5f - 0.5f * sq};
    float val = 0.f, wsum = 0.f;
    const float* yb = yfr + (size_t)b * NFP * 512;
    #pragma unroll
    for (int dm = 0; dm < 4; ++dm) {
        int mm = m0 - dm;
        if (mm >= 0 && mm < NF) {
            val += yb[(size_t)mm * 512 + q + 128 * dm];
            wsum += w4[dm] * w4[dm];
        }
    }
    out[i] = val / fmaxf(wsum, 1e-10f);
}

extern "C" void kernel_launch(void* const* d_in, const int* in_sizes, int n_in,
                              void* d_out, int out_size, void* d_ws, size_t ws_size,
                              hipStream_t stream) {
    const float* x  = (const float*)d_in[0];
    const float* w1 = (const float*)d_in[1];
    const float* b1 = (const float*)d_in[2];
    const float* w2 = (const float*)d_in[3];
    const float* b2 = (const float*)d_in[4];

    float* ws = (float*)d_ws;
    size_t off = 0;
    float*  tw   = ws + off; off += 512;
    float2* X    = (float2*)(ws + off); off += (size_t)BATCH * FP * NF * CH * 2;
    float*  feat = ws + off; off += (size_t)BATCH * NF * FP;     // feat+h reused as `part`
    float*  h    = ws + off; off += (size_t)BATCH * NF * HID;
    float*  mo   = ws + off; off += (size_t)BATCH * NF * HID;
    float2* wc   = (float2*)(ws + off); off += (size_t)BATCH * FP * CH * 2;
    float*  yfr  = ws + off; off += (size_t)BATCH * NFP * 512;

    // part: [8][8][256][72] float2 = 9.44 MB <= feat+h (12.3 MB), both dead after mlp2
    float2* part = (float2*)feat;

    k_tables<<<2, 256, 0, stream>>>(tw);
    k_stft<<<BATCH * CH * NGRP, 256, 0, stream>>>(x, tw, X, feat);
    k_mlp1<<<BATCH * NF / 8, 512, 0, stream>>>(feat, w1, b1, h);
    k_mlp2<<<BATCH * NF / 8, 512, 0, stream>>>(h, w2, b2, mo);
    k_cov<<<BATCH * 4 * CNCK, 512, 0, stream>>>(X, mo, part);
    k_cov_solve2<<<BATCH * 32, 512, 0, stream>>>(part, wc);
    k_istft_bf<<<BATCH * NGRP, 512, 0, stream>>>(X, wc, yfr);
    k_out<<<(BATCH * TLEN + 255) / 256, 256, 0, stream>>>(yfr, (float*)d_out);
}

// Round 7
// 227.349 us; speedup vs baseline: 7.7401x; 1.0042x over previous
//
#include <hip/hip_runtime.h>
#include <math.h>

#define NFFT 512
#define HOP  128
#define PADW 256
#define TLEN 64000
#define NF   501
#define NFP  504    // padded frame count for yfr rows
#define FP   256
#define CH   8
#define BATCH 8
#define HID  512
#define FPB  8      // frames per block (stft/istft)
#define NGRP 63     // ceil(NF/FPB)
#define CNCK 8      // cov n-chunks
#define CCK  63     // ceil(NF/CNCK)
#define NSTG 4      // cov frames staged per sync round

// ---------------- tables: hann window (used by stft staging) ----------------
__global__ void k_tables(float* tw) {
    int j = threadIdx.x + blockIdx.x * blockDim.x;
    if (j < 512) {
        float ang = (float)(2.0 * M_PI * (double)j / 512.0);
        tw[j] = 0.5f - 0.5f * cosf(ang);
    }
}

// ---------------- STFT: two-stage CT (512 = 16x32), LDS-instruction-minimized ----------------
// Stage B: thread=(t1,jj) owns 1 row, 2 bins (j=jj, jj+16 via (-1)^t2 sign trick).
// Stage C: thread=(j,fp,h) owns 4 bins x 2 frames (k+128 via (-i)^t1 swap/negate trick).
// Yl cells: (t1*32+j), 5 float4 stride (80 B: 16B-aligned, bank-spread), [fp] = frame-pair.
__global__ __launch_bounds__(256) void k_stft(const float* __restrict__ x,
                                              const float* __restrict__ tw,
                                              float2* __restrict__ X,
                                              float* __restrict__ feat) {
    __shared__ float sT[512][8];          // [t][frame] 16 KB
    __shared__ float4 Yl4[16 * 32 * 5];   // 40 KB
    int blk = blockIdx.x;
    int g = blk % NGRP;
    int bc = blk / NGRP;
    int c = bc % CH, b = bc / CH;
    int m0 = g * FPB;
    int tid = threadIdx.x;
    const float* xp = x + (size_t)(b * CH + c) * TLEN;

    // stage A: load 8 windowed frames
    for (int i = tid; i < FPB * 512; i += 256) {
        int t = i >> 3, fr = i & 7;
        int j = (m0 + fr) * HOP + t - PADW;   // reflect pad
        if (j < 0) j = -j;
        if (j >= TLEN) j = 2 * (TLEN - 1) - j;
        sT[t][fr] = xp[j] * tw[t];
    }
    __syncthreads();

    // stage B: Y[t1][j] = sum_t2 sT[t1+16t2] e^{-i 2pi j t2/32}
    {
        int t1 = tid >> 4, jj = tid & 15;     // j = jj and jj+16
        float sj, cj;
        sincosf((float)jj * (float)(2.0 * M_PI / 32.0), &sj, &cj);
        float stepc = cj, steps = -sj;        // e^{-i 2pi jj/32}
        float y0r[8], y0i[8], y1r[8], y1i[8];
        #pragma unroll
        for (int fr = 0; fr < 8; ++fr) { y0r[fr] = 0.f; y0i[fr] = 0.f; y1r[fr] = 0.f; y1i[fr] = 0.f; }
        float cr = 1.f, ci = 0.f;
        for (int t2 = 0; t2 < 32; t2 += 2) {
            {   // even t2: j+16 sign = +
                const float4 a0 = *(const float4*)&sT[t1 + 16 * t2][0];
                const float4 a1 = *(const float4*)&sT[t1 + 16 * t2][4];
                float av[8] = {a0.x, a0.y, a0.z, a0.w, a1.x, a1.y, a1.z, a1.w};
                #pragma unroll
                for (int fr = 0; fr < 8; ++fr) {
                    y0r[fr] += av[fr] * cr; y0i[fr] += av[fr] * ci;
                    y1r[fr] += av[fr] * cr; y1i[fr] += av[fr] * ci;
                }
                float ncr = cr * stepc - ci * steps;
                ci = cr * steps + ci * stepc;
                cr = ncr;
            }
            {   // odd t2: j+16 sign = -
                const float4 a0 = *(const float4*)&sT[t1 + 16 * t2 + 16][0];
                const float4 a1 = *(const float4*)&sT[t1 + 16 * t2 + 16][4];
                float av[8] = {a0.x, a0.y, a0.z, a0.w, a1.x, a1.y, a1.z, a1.w};
                #pragma unroll
                for (int fr = 0; fr < 8; ++fr) {
                    y0r[fr] += av[fr] * cr; y0i[fr] += av[fr] * ci;
                    y1r[fr] -= av[fr] * cr; y1i[fr] -= av[fr] * ci;
                }
                float ncr = cr * stepc - ci * steps;
                ci = cr * steps + ci * stepc;
                cr = ncr;
            }
        }
        int cell0 = t1 * 32 + jj, cell1 = cell0 + 16;
        #pragma unroll
        for (int fp = 0; fp < 4; ++fp) {
            Yl4[cell0 * 5 + fp] = make_float4(y0r[2 * fp], y0i[2 * fp], y0r[2 * fp + 1], y0i[2 * fp + 1]);
            Yl4[cell1 * 5 + fp] = make_float4(y1r[2 * fp], y1i[2 * fp], y1r[2 * fp + 1], y1i[2 * fp + 1]);
        }
    }
    __syncthreads();

    // stage C: X[k] = sum_t1 e^{-i 2pi k t1/512} Y[t1][k mod 32]
    {
        int j = tid >> 3, fp = (tid >> 1) & 3, h = tid & 1;
        int kb0 = j + 32 * h, kb1 = kb0 + 64;
        if (j == 0 && h == 0) { kb0 = 64; kb1 = 128; }   // bin set {64,192,128,256}
        float s0, c0, s1, c1;
        sincosf((float)kb0 * (float)(2.0 * M_PI / 512.0), &s0, &c0);
        sincosf((float)kb1 * (float)(2.0 * M_PI / 512.0), &s1, &c1);
        float st0c = c0, st0s = -s0;          // e^{-i 2pi kb0/512}
        float st1c = c1, st1s = -s1;
        float ar[4][2], ai[4][2];             // [bin: kb0, kb0+128, kb1, kb1+128][frame e]
        #pragma unroll
        for (int q = 0; q < 4; ++q) { ar[q][0] = 0.f; ai[q][0] = 0.f; ar[q][1] = 0.f; ai[q][1] = 0.f; }
        float cr0 = 1.f, ci0 = 0.f, cr1 = 1.f, ci1 = 0.f;
        #pragma unroll
        for (int t1q = 0; t1q < 4; ++t1q) {
            #pragma unroll
            for (int r = 0; r < 4; ++r) {     // t1 = 4*t1q + r; (-i)^t1 case = r
                int t1 = t1q * 4 + r;
                float4 yv = Yl4[(t1 * 32 + j) * 5 + fp];
                // bin kb0: tw = (cr0, ci0)
                ar[0][0] += yv.x * cr0 - yv.y * ci0;
                ai[0][0] += yv.x * ci0 + yv.y * cr0;
                ar[0][1] += yv.z * cr0 - yv.w * ci0;
                ai[0][1] += yv.z * ci0 + yv.w * cr0;
                // bin kb0+128: tw * (-i)^r
                float a0c = (r == 0) ? cr0 : (r == 1) ? ci0 : (r == 2) ? -cr0 : -ci0;
                float b0c = (r == 0) ? ci0 : (r == 1) ? -cr0 : (r == 2) ? -ci0 : cr0;
                ar[1][0] += yv.x * a0c - yv.y * b0c;
                ai[1][0] += yv.x * b0c + yv.y * a0c;
                ar[1][1] += yv.z * a0c - yv.w * b0c;
                ai[1][1] += yv.z * b0c + yv.w * a0c;
                // bin kb1: tw = (cr1, ci1)
                ar[2][0] += yv.x * cr1 - yv.y * ci1;
                ai[2][0] += yv.x * ci1 + yv.y * cr1;
                ar[2][1] += yv.z * cr1 - yv.w * ci1;
                ai[2][1] += yv.z * ci1 + yv.w * cr1;
                // bin kb1+128: tw * (-i)^r
                float a1c = (r == 0) ? cr1 : (r == 1) ? ci1 : (r == 2) ? -cr1 : -ci1;
                float b1c = (r == 0) ? ci1 : (r == 1) ? -cr1 : (r == 2) ? -ci1 : cr1;
                ar[3][0] += yv.x * a1c - yv.y * b1c;
                ai[3][0] += yv.x * b1c + yv.y * a1c;
                ar[3][1] += yv.z * a1c - yv.w * b1c;
                ai[3][1] += yv.z * b1c + yv.w * a1c;
                // rotate both recurrences
                float n0 = cr0 * st0c - ci0 * st0s; ci0 = cr0 * st0s + ci0 * st0c; cr0 = n0;
                float n1 = cr1 * st1c - ci1 * st1s; ci1 = cr1 * st1s + ci1 * st1c; cr1 = n1;
            }
        }
        int fbin[4] = {kb0 - 1, kb0 + 127, kb1 - 1, kb1 + 127};
        #pragma unroll
        for (int q = 0; q < 4; ++q) {
            #pragma unroll
            for (int e = 0; e < 2; ++e) {
                int m = m0 + fp * 2 + e;
                if (m < NF) {
                    X[((size_t)(b * NF + m) * CH + c) * FP + fbin[q]] = make_float2(ar[q][e], ai[q][e]);
                    if (c == 0)
                        feat[((size_t)b * NF + m) * FP + fbin[q]] = sqrtf(ar[q][e] * ar[q][e] + ai[q][e] * ai[q][e]);
                }
            }
        }
    }
}

// ---------------- MLP layer 1: activations via uniform (scalar) loads ----------------
__global__ __launch_bounds__(512) void k_mlp1(const float* __restrict__ feat,
                                              const float* __restrict__ w1,
                                              const float* __restrict__ b1,
                                              float* __restrict__ h) {
    int row0 = blockIdx.x * 8;
    int j = threadIdx.x;
    const float* fr0 = feat + (size_t)row0 * FP;
    float bj = b1[j];
    float acc[8];
    #pragma unroll
    for (int r = 0; r < 8; ++r) acc[r] = bj;
    #pragma unroll 4
    for (int f = 0; f < FP; ++f) {
        float wv = w1[(size_t)f * HID + j];
        #pragma unroll
        for (int r = 0; r < 8; ++r) acc[r] += fr0[r * FP + f] * wv;
    }
    #pragma unroll
    for (int r = 0; r < 8; ++r)
        h[(size_t)(row0 + r) * HID + j] = fmaxf(acc[r], 0.f);
}

// ---------------- MLP layer 2 ----------------
__global__ __launch_bounds__(512) void k_mlp2(const float* __restrict__ h,
                                              const float* __restrict__ w2,
                                              const float* __restrict__ b2,
                                              float* __restrict__ mo) {
    int row0 = blockIdx.x * 8;
    int j = threadIdx.x;
    const float* hr0 = h + (size_t)row0 * HID;
    float bj = b2[j];
    float acc[8];
    #pragma unroll
    for (int r = 0; r < 8; ++r) acc[r] = bj;
    #pragma unroll 4
    for (int f = 0; f < HID; ++f) {
        float wv = w2[(size_t)f * HID + j];
        #pragma unroll
        for (int r = 0; r < 8; ++r) acc[r] += hr0[r * HID + f] * wv;
    }
    #pragma unroll
    for (int r = 0; r < 8; ++r)
        mo[(size_t)(row0 + r) * HID + j] = 1.f / (1.f + expf(-acc[r]));
}

// ---------------- covariance partials: 4 frames staged per sync round ----------------
// part layout: [nc][b][f][72] float2 : slots 0..63 = R[c][d], 64..71 = rhs[c]
__global__ __launch_bounds__(512) void k_cov(const float2* __restrict__ X,
                                             const float* __restrict__ mo,
                                             float2* __restrict__ part) {
    int blk = blockIdx.x;               // ((b*4 + ftile)*8 + nc)
    int nc = blk & 7;
    int ftile = (blk >> 3) & 3;
    int b = blk >> 5;
    int tid = threadIdx.x;
    int c = tid >> 6;
    int ft = tid & 63;
    int f = ftile * 64 + ft;
    int n0 = nc * CCK;
    int n1 = n0 + CCK; if (n1 > NF) n1 = NF;

    __shared__ float2 vbuf[2][NSTG][CH][64];   // 32 KB

    float ar[8], ai[8];
    #pragma unroll
    for (int d = 0; d < 8; ++d) { ar[d] = 0.f; ai[d] = 0.f; }
    float rr = 0.f, ri = 0.f;

    const float2* Xb = X + (size_t)b * NF * CH * FP;
    const float* mb = mo + (size_t)b * NF * HID;

    #pragma unroll
    for (int r = 0; r < NSTG; ++r) {
        int n = n0 + r;
        if (n < n1) vbuf[0][r][c][ft] = Xb[(size_t)(n * CH + c) * FP + f];
    }
    __syncthreads();
    int cur = 0;
    for (int nb = n0; nb < n1; nb += NSTG) {
        int nbn = nb + NSTG;
        float2 nx[NSTG];
        #pragma unroll
        for (int r = 0; r < NSTG; ++r) {
            int n = nbn + r;
            if (n < n1) nx[r] = Xb[(size_t)(n * CH + c) * FP + f];
        }
        float mts[NSTG], mns[NSTG];
        #pragma unroll
        for (int r = 0; r < NSTG; ++r) {
            int n = nb + r;
            if (n < n1) {
                mts[r] = mb[(size_t)n * HID + f];
                mns[r] = mb[(size_t)n * HID + FP + f];
            }
        }
        #pragma unroll
        for (int r = 0; r < NSTG; ++r) {
            int n = nb + r;
            if (n < n1) {
                float mt = mts[r], mn = mns[r];
                float w = mt + mn;
                float2 xc = vbuf[cur][r][c][ft];
                #pragma unroll
                for (int d = 0; d < 8; ++d) {
                    float2 xd = vbuf[cur][r][d][ft];
                    float pr = xc.x * xd.x + xc.y * xd.y;   // xc * conj(xd)
                    float pi = xc.y * xd.x - xc.x * xd.y;
                    ar[d] += w * pr; ai[d] += w * pi;
                    if (d == 0) { rr += mt * pr; ri += mt * pi; }
                }
            }
        }
        if (nbn < n1) {
            #pragma unroll
            for (int r = 0; r < NSTG; ++r) {
                int n = nbn + r;
                if (n < n1) vbuf[cur ^ 1][r][c][ft] = nx[r];
            }
        }
        __syncthreads();
        cur ^= 1;
    }
    float2* pp = part + (((size_t)nc * BATCH + b) * FP + f) * 72;
    #pragma unroll
    for (int d = 0; d < 8; ++d)
        pp[c * 8 + d] = make_float2(ar[d], ai[d]);
    pp[64 + c] = make_float2(rr, ri);
}

// ---------------- reduce partials + 8x8 complex solve: block = (b, fgroup8) ----------------
__global__ __launch_bounds__(512) void k_cov_solve2(const float2* __restrict__ part,
                                                    float2* __restrict__ wc) {
    int blk = blockIdx.x;          // b*32 + fg
    int fg = blk & 31;
    int b = blk >> 5;
    int tid = threadIdx.x;
    int c = tid >> 6, d = (tid >> 3) & 7, fl = tid & 7;
    int f = fg * 8 + fl;
    float ar = 0.f, ai = 0.f, rr = 0.f, ri = 0.f;
    const float2* pb = part + ((size_t)b * FP + f) * 72;
    #pragma unroll
    for (int nc = 0; nc < CNCK; ++nc) {
        const float2* p = pb + (size_t)nc * BATCH * FP * 72;
        float2 v = p[c * 8 + d];
        ar += v.x; ai += v.y;
        if (d == 0) { float2 u = p[64 + c]; rr += u.x; ri += u.y; }
    }
    __shared__ float2 Am[8][73];
    __shared__ float2 rh[8][8];
    __shared__ float2 sl[8][9];
    Am[fl][c * 9 + d] = make_float2(ar, ai);
    if (d == 0) rh[fl][c] = make_float2(rr, ri);
    __syncthreads();
    if (tid < 8) {
        int ln = tid;
        float2* A = Am[ln];
        float2* r = rh[ln];
        float2* sol = sl[ln];
        for (int kk = 0; kk < 8; ++kk) {
            float2 pp = A[kk * 9 + kk];
            float ip = 1.f / (pp.x * pp.x + pp.y * pp.y);
            float invr = pp.x * ip, invi = -pp.y * ip;
            for (int i = kk + 1; i < 8; ++i) {
                float2 aik = A[i * 9 + kk];
                float fr2 = aik.x * invr - aik.y * invi;
                float fi2 = aik.x * invi + aik.y * invr;
                for (int jj = kk; jj < 8; ++jj) {
                    float2 ak = A[kk * 9 + jj];
                    A[i * 9 + jj].x -= fr2 * ak.x - fi2 * ak.y;
                    A[i * 9 + jj].y -= fr2 * ak.y + fi2 * ak.x;
                }
                r[i].x -= fr2 * r[kk].x - fi2 * r[kk].y;
                r[i].y -= fr2 * r[kk].y + fi2 * r[kk].x;
            }
        }
        for (int kk = 7; kk >= 0; --kk) {
            float sr = r[kk].x, si = r[kk].y;
            for (int jj = kk + 1; jj < 8; ++jj) {
                float2 ak = A[kk * 9 + jj];
                float2 xj = sol[jj];
                sr -= ak.x * xj.x - ak.y * xj.y;
                si -= ak.x * xj.y + ak.y * xj.x;
            }
            float2 pp = A[kk * 9 + kk];
            float ip = 1.f / (pp.x * pp.x + pp.y * pp.y);
            sol[kk].x = (sr * pp.x + si * pp.y) * ip;
            sol[kk].y = (si * pp.x - sr * pp.y) * ip;
        }
        for (int cc = 0; cc < 8; ++cc)   // wc layout [b][c][f], store conj
            wc[((size_t)b * CH + cc) * FP + fg * 8 + ln] = make_float2(sol[cc].x, -sol[cc].y);
    }
}

// ---------------- fused beamform + ISTFT: per-frame windowed iDFT rows, no atomics ----------------
__global__ __launch_bounds__(512) void k_istft_bf(const float2* __restrict__ X,
                                                  const float2* __restrict__ wc,
                                                  float* __restrict__ yfr) {
    __shared__ float2 Zp[4 * 512];          // [sig][k] Hermitian-combined spectra
    __shared__ float2 Gl[16 * 32 * 5];      // [k1][tau][sig] pad 5
    int blk = blockIdx.x;
    int g = blk % NGRP, b = blk / NGRP;
    int m0 = g * FPB;
    int tid = threadIdx.x;

    if (tid < 4) Zp[tid * 512] = make_float2(0.f, 0.f);   // k = 0 (DC dropped)
    const float2* Xb0 = X + (size_t)b * NF * CH * FP;
    const float2* wcb = wc + (size_t)b * CH * FP;
    #pragma unroll
    for (int half = 0; half < 2; ++half) {
        int i = half * 512 + tid;
        int sig = i >> 8, kp = i & 255;     // bin kp -> k = kp+1
        int ma = m0 + 2 * sig, mb_ = ma + 1;
        float2 Xa = make_float2(0.f, 0.f), Xb = make_float2(0.f, 0.f);
        if (ma < NF) {
            #pragma unroll
            for (int c = 0; c < 8; ++c) {
                float2 xv = Xb0[(size_t)(ma * CH + c) * FP + kp];
                float2 wv = wcb[c * FP + kp];
                Xa.x += xv.x * wv.x - xv.y * wv.y;
                Xa.y += xv.x * wv.y + xv.y * wv.x;
            }
        }
        if (mb_ < NF) {
            #pragma unroll
            for (int c = 0; c < 8; ++c) {
                float2 xv = Xb0[(size_t)(mb_ * CH + c) * FP + kp];
                float2 wv = wcb[c * FP + kp];
                Xb.x += xv.x * wv.x - xv.y * wv.y;
                Xb.y += xv.x * wv.y + xv.y * wv.x;
            }
        }
        int k = kp + 1;
        if (k == 256) {
            Zp[sig * 512 + 256] = make_float2(Xa.x, Xb.x);   // Nyquist: real parts only
        } else {
            Zp[sig * 512 + k]       = make_float2(Xa.x - Xb.y, Xa.y + Xb.x);
            Zp[sig * 512 + 512 - k] = make_float2(Xa.x + Xb.y, Xb.x - Xa.y);
        }
    }
    __syncthreads();

    // stage 1: G[k1][tau] = sum_{k2} Zp[k1+16*k2] e^{+i 2pi k2 tau/32}
    {
        int k1 = tid >> 5, tau = tid & 31;
        float sa, ca;
        sincosf((float)tau * (float)(2.0 * M_PI / 32.0), &sa, &ca);
        float stepc = ca, steps = sa;
        float gr[4], gi[4];
        #pragma unroll
        for (int s = 0; s < 4; ++s) { gr[s] = 0.f; gi[s] = 0.f; }
        float cr = 1.f, ci = 0.f;
        #pragma unroll 4
        for (int k2 = 0; k2 < 32; ++k2) {
            int k = k1 + 16 * k2;
            #pragma unroll
            for (int s = 0; s < 4; ++s) {
                float2 z = Zp[s * 512 + k];
                gr[s] += z.x * cr - z.y * ci;
                gi[s] += z.x * ci + z.y * cr;
            }
            float ncr = cr * stepc - ci * steps;
            ci = cr * steps + ci * stepc;
            cr = ncr;
        }
        #pragma unroll
        for (int s = 0; s < 4; ++s)
            Gl[(k1 * 32 + tau) * 5 + s] = make_float2(gr[s], gi[s]);
    }
    __syncthreads();

    // stage 2: y_pair[t] = sum_{k1} G[k1][t&31] e^{+i 2pi k1 t/512}; Re->frame a, Im->frame b
    int t = tid;
    int tau = t & 31;
    float sa2, ca2;
    sincosf((float)t * (float)(2.0 * M_PI / 512.0), &sa2, &ca2);
    float stepc = ca2, steps = sa2;
    float accr[4], acci[4];
    #pragma unroll
    for (int s = 0; s < 4; ++s) { accr[s] = 0.f; acci[s] = 0.f; }
    float cr = 1.f, ci = 0.f;
    #pragma unroll 4
    for (int k1 = 0; k1 < 16; ++k1) {
        #pragma unroll
        for (int s = 0; s < 4; ++s) {
            float2 gv = Gl[(k1 * 32 + tau) * 5 + s];
            accr[s] += gv.x * cr - gv.y * ci;
            acci[s] += gv.x * ci + gv.y * cr;
        }
        float ncr = cr * stepc - ci * steps;
        ci = cr * steps + ci * stepc;
        cr = ncr;
    }
    float wv = (0.5f - 0.5f * ca2) * (1.f / 512.f);   // hann(t) / 512
    #pragma unroll
    for (int s = 0; s < 4; ++s) {
        int ma = m0 + 2 * s, mb_ = ma + 1;
        if (ma < NF)  yfr[((size_t)b * NFP + ma) * 512 + t] = accr[s] * wv;
        if (mb_ < NF) yfr[((size_t)b * NFP + mb_) * 512 + t] = acci[s] * wv;
    }
}

// ---------------- gather overlap-add + wsum normalize ----------------
__global__ __launch_bounds__(256) void k_out(const float* __restrict__ yfr,
                                             float* __restrict__ out) {
    int i = blockIdx.x * blockDim.x + threadIdx.x;
    if (i >= BATCH * TLEN) return;
    int b = i / TLEN;
    int t = i - b * TLEN;
    int p = t + PADW;
    int q = p & 127;
    int m0 = p >> 7;
    float sq, cq;
    sincosf((float)q * (float)(2.0 * M_PI / 512.0), &sq, &cq);
    float w4[4] = {0.5f - 0.5f * cq, 0.5f + 0.5f * sq, 0.5f + 0.5f * cq, 0.5f - 0.5f * sq};
    float val = 0.f, wsum = 0.f;
    const float* yb = yfr + (size_t)b * NFP * 512;
    #pragma unroll
    for (int dm = 0; dm < 4; ++dm) {
        int mm = m0 - dm;
        if (mm >= 0 && mm < NF) {
            val += yb[(size_t)mm * 512 + q + 128 * dm];
            wsum += w4[dm] * w4[dm];
        }
    }
    out[i] = val / fmaxf(wsum, 1e-10f);
}

extern "C" void kernel_launch(void* const* d_in, const int* in_sizes, int n_in,
                              void* d_out, int out_size, void* d_ws, size_t ws_size,
                              hipStream_t stream) {
    const float* x  = (const float*)d_in[0];
    const float* w1 = (const float*)d_in[1];
    const float* b1 = (const float*)d_in[2];
    const float* w2 = (const float*)d_in[3];
    const float* b2 = (const float*)d_in[4];

    float* ws = (float*)d_ws;
    size_t off = 0;
    float*  tw   = ws + off; off += 512;
    float2* X    = (float2*)(ws + off); off += (size_t)BATCH * FP * NF * CH * 2;
    float*  feat = ws + off; off += (size_t)BATCH * NF * FP;     // feat+h reused as `part`
    float*  h    = ws + off; off += (size_t)BATCH * NF * HID;
    float*  mo   = ws + off; off += (size_t)BATCH * NF * HID;
    float2* wc   = (float2*)(ws + off); off += (size_t)BATCH * FP * CH * 2;
    float*  yfr  = ws + off; off += (size_t)BATCH * NFP * 512;

    // part: [8][8][256][72] float2 = 9.44 MB <= feat+h (12.3 MB), both dead after mlp2
    float2* part = (float2*)feat;

    k_tables<<<2, 256, 0, stream>>>(tw);
    k_stft<<<BATCH * CH * NGRP, 256, 0, stream>>>(x, tw, X, feat);
    k_mlp1<<<BATCH * NF / 8, 512, 0, stream>>>(feat, w1, b1, h);
    k_mlp2<<<BATCH * NF / 8, 512, 0, stream>>>(h, w2, b2, mo);
    k_cov<<<BATCH * 4 * CNCK, 512, 0, stream>>>(X, mo, part);
    k_cov_solve2<<<BATCH * 32, 512, 0, stream>>>(part, wc);
    k_istft_bf<<<BATCH * NGRP, 512, 0, stream>>>(X, wc, yfr);
    k_out<<<(BATCH * TLEN + 255) / 256, 256, 0, stream>>>(yfr, (float*)d_out);
}

// Round 8
// 181.543 us; speedup vs baseline: 9.6930x; 1.2523x over previous
//
#include <hip/hip_runtime.h>
#include <math.h>

#define NFFT 512
#define HOP  128
#define PADW 256
#define TLEN 64000
#define NF   501
#define NFP  504    // padded frame count for yfr rows
#define FP   256
#define CH   8
#define BATCH 8
#define HID  512
#define FPB  8      // frames per block (stft/istft)
#define NGRP 63     // ceil(NF/FPB)
#define CNCK 8      // cov n-chunks
#define CCK  63     // ceil(NF/CNCK)
#define NSTG 4      // cov frames staged per sync round

#define S2C 0.70710678118654752f

// ---------------- complex helpers ----------------
__device__ __forceinline__ float2 cadd(float2 a, float2 b) { return make_float2(a.x + b.x, a.y + b.y); }
__device__ __forceinline__ float2 csub(float2 a, float2 b) { return make_float2(a.x - b.x, a.y - b.y); }
__device__ __forceinline__ float2 cmul(float2 a, float2 b) { return make_float2(a.x * b.x - a.y * b.y, a.x * b.y + a.y * b.x); }
__device__ __forceinline__ float2 mulnegi(float2 a) { return make_float2(a.y, -a.x); }   // a * (-i)

// forward DFT-8: v[k] = sum_a u[a] * W8^{a k}, W8 = e^{-2pi i/8}
__device__ __forceinline__ void dft8(const float2 u[8], float2 v[8]) {
    float2 a0 = cadd(u[0], u[4]), a1 = cadd(u[1], u[5]), a2 = cadd(u[2], u[6]), a3 = cadd(u[3], u[7]);
    float2 b0 = csub(u[0], u[4]), b1 = csub(u[1], u[5]), b2 = csub(u[2], u[6]), b3 = csub(u[3], u[7]);
    float2 c0 = cadd(a0, a2), c1 = csub(a0, a2), c2 = cadd(a1, a3), c3 = csub(a1, a3);
    v[0] = cadd(c0, c2); v[4] = csub(c0, c2);
    float2 nic3 = mulnegi(c3);
    v[2] = cadd(c1, nic3); v[6] = csub(c1, nic3);
    float2 d1 = make_float2(S2C * (b1.x + b1.y), S2C * (b1.y - b1.x));   // W8^1 * b1
    float2 d2 = mulnegi(b2);                                             // W8^2 * b2
    float2 d3 = make_float2(S2C * (b3.y - b3.x), -S2C * (b3.x + b3.y));  // W8^3 * b3
    float2 e0 = cadd(b0, d2), e1 = csub(b0, d2), e2 = cadd(d1, d3), e3 = csub(d1, d3);
    v[1] = cadd(e0, e2); v[5] = csub(e0, e2);
    float2 nie3 = mulnegi(e3);
    v[3] = cadd(e1, nie3); v[7] = csub(e1, nie3);
}

__device__ __forceinline__ int refl(int j) {
    j = (j < 0) ? -j : j;
    j = (j >= TLEN) ? 2 * (TLEN - 1) - j : j;
    return j;
}

// ---------------- tables: hann window ----------------
__global__ void k_tables(float* tw) {
    int j = threadIdx.x + blockIdx.x * blockDim.x;
    if (j < 512) {
        float ang = (float)(2.0 * M_PI * (double)j / 512.0);
        tw[j] = 0.5f - 0.5f * cosf(ang);
    }
}

// ---------------- STFT: radix-8^3 Stockham FFT on frame-pairs (z = fa + i fb) ----------------
// 8 frames = 4 pairs per block; 256 thr = 4 sig x 64 dft; one DFT-8 per thread per stage.
// A: z (linear 512) then U2 ((8k0+k1)*9+cd); B: U1 (k0*68+8b+cd) then Z (linear).
#define A_S 580
#define B_S 544
__global__ __launch_bounds__(256, 4) void k_stft(const float* __restrict__ x,
                                                 const float* __restrict__ tw,
                                                 float2* __restrict__ X,
                                                 float* __restrict__ feat) {
    __shared__ float2 Abuf[4 * A_S];
    __shared__ float2 Bbuf[4 * B_S];
    __shared__ float2 Twd[512];
    int blk = blockIdx.x;
    int g = blk % NGRP;
    int bc = blk / NGRP;
    int c = bc % CH, b = bc / CH;
    int m0 = g * FPB;
    int tid = threadIdx.x;
    const float* xp = x + (size_t)(b * CH + c) * TLEN;

    // twiddle table: W512^e = (cos, -sin)(2pi e/512)
    #pragma unroll
    for (int r = 0; r < 2; ++r) {
        int e = tid + 256 * r;
        float se, ce;
        sincosf((float)e * (float)(2.0 * M_PI / 512.0), &se, &ce);
        Twd[e] = make_float2(ce, -se);
    }

    // build z[sig][t] = w[t] * (x_a[t] + i x_b[t]), pairs (m0+2sig, m0+2sig+1)
    #pragma unroll
    for (int r = 0; r < 8; ++r) {
        int flat = r * 256 + tid;
        int sig = flat >> 9, t = flat & 511;
        int posa = (m0 + 2 * sig) * HOP + t - PADW;
        float xa = xp[refl(posa)];
        float xb = xp[refl(posa + HOP)];
        float w = tw[t];
        Abuf[sig * A_S + t] = make_float2(xa * w, xb * w);
    }
    __syncthreads();

    int sig = tid >> 6, dft = tid & 63;
    float2 u[8], v[8];

    // stage 1: dft = 8b+cd; read z[64a + dft], DFT8 over a -> k0; write U1[k0*68 + dft]
    {
        const float2* Az = &Abuf[sig * A_S];
        float2* Bu = &Bbuf[sig * B_S];
        #pragma unroll
        for (int a = 0; a < 8; ++a) u[a] = Az[64 * a + dft];
        dft8(u, v);
        #pragma unroll
        for (int k0 = 0; k0 < 8; ++k0) Bu[k0 * 68 + dft] = v[k0];
    }
    __syncthreads();

    // stage 2: dft = (k0, cd); read U1[k0*68 + 8b + cd], twiddle W512^{8 b k0}, DFT8 over b -> k1
    // write U2[(8k0+k1)*9 + cd]
    {
        int k0 = dft >> 3, cd = dft & 7;
        const float2* Bu = &Bbuf[sig * B_S];
        float2* Au = &Abuf[sig * A_S];
        #pragma unroll
        for (int bb = 0; bb < 8; ++bb) u[bb] = Bu[k0 * 68 + 8 * bb + cd];
        #pragma unroll
        for (int bb = 1; bb < 8; ++bb) u[bb] = cmul(u[bb], Twd[(8 * bb * k0) & 511]);
        dft8(u, v);
        #pragma unroll
        for (int k1 = 0; k1 < 8; ++k1) Au[(8 * k0 + k1) * 9 + cd] = v[k1];
    }
    __syncthreads();

    // stage 3: dft = (k0 = dft>>3, k1 = dft&7); read U2[dft*9 + cd], twiddle W512^{cd(k0+8k1)},
    // DFT8 over cd -> k2; write Z[k0 + 8k1 + 64k2]
    {
        int k0 = dft >> 3, k1 = dft & 7;
        int kk = k0 + 8 * k1;
        const float2* Au = &Abuf[sig * A_S];
        float2* Bz = &Bbuf[sig * B_S];
        #pragma unroll
        for (int cd = 0; cd < 8; ++cd) u[cd] = Au[dft * 9 + cd];
        #pragma unroll
        for (int cd = 1; cd < 8; ++cd) u[cd] = cmul(u[cd], Twd[(cd * kk) & 511]);
        dft8(u, v);
        #pragma unroll
        for (int k2 = 0; k2 < 8; ++k2) Bz[kk + 64 * k2] = v[k2];
    }
    __syncthreads();

    // unpack: Fa[k] = (Z[k]+conj(Z[512-k]))/2, Fb[k] = (Z[k]-conj(Z[512-k]))/(2i); k = kp+1
    {
        int kp = tid;
        int k = kp + 1;
        #pragma unroll
        for (int s = 0; s < 4; ++s) {
            float2 z1 = Bbuf[s * B_S + k];
            float2 z2 = Bbuf[s * B_S + (512 - k)];
            float Ar = 0.5f * (z1.x + z2.x);
            float Ai = 0.5f * (z1.y - z2.y);
            float Br = 0.5f * (z1.y + z2.y);
            float Bi = 0.5f * (z2.x - z1.x);
            int ma = m0 + 2 * s, mb_ = ma + 1;
            if (ma < NF) {
                X[((size_t)(b * NF + ma) * CH + c) * FP + kp] = make_float2(Ar, Ai);
                if (c == 0) feat[((size_t)b * NF + ma) * FP + kp] = sqrtf(Ar * Ar + Ai * Ai);
            }
            if (mb_ < NF) {
                X[((size_t)(b * NF + mb_) * CH + c) * FP + kp] = make_float2(Br, Bi);
                if (c == 0) feat[((size_t)b * NF + mb_) * FP + kp] = sqrtf(Br * Br + Bi * Bi);
            }
        }
    }
}

// ---------------- MLP layer 1: activations via uniform (scalar) loads ----------------
__global__ __launch_bounds__(512) void k_mlp1(const float* __restrict__ feat,
                                              const float* __restrict__ w1,
                                              const float* __restrict__ b1,
                                              float* __restrict__ h) {
    int row0 = blockIdx.x * 8;
    int j = threadIdx.x;
    const float* fr0 = feat + (size_t)row0 * FP;
    float bj = b1[j];
    float acc[8];
    #pragma unroll
    for (int r = 0; r < 8; ++r) acc[r] = bj;
    #pragma unroll 4
    for (int f = 0; f < FP; ++f) {
        float wv = w1[(size_t)f * HID + j];
        #pragma unroll
        for (int r = 0; r < 8; ++r) acc[r] += fr0[r * FP + f] * wv;
    }
    #pragma unroll
    for (int r = 0; r < 8; ++r)
        h[(size_t)(row0 + r) * HID + j] = fmaxf(acc[r], 0.f);
}

// ---------------- MLP layer 2 ----------------
__global__ __launch_bounds__(512) void k_mlp2(const float* __restrict__ h,
                                              const float* __restrict__ w2,
                                              const float* __restrict__ b2,
                                              float* __restrict__ mo) {
    int row0 = blockIdx.x * 8;
    int j = threadIdx.x;
    const float* hr0 = h + (size_t)row0 * HID;
    float bj = b2[j];
    float acc[8];
    #pragma unroll
    for (int r = 0; r < 8; ++r) acc[r] = bj;
    #pragma unroll 4
    for (int f = 0; f < HID; ++f) {
        float wv = w2[(size_t)f * HID + j];
        #pragma unroll
        for (int r = 0; r < 8; ++r) acc[r] += hr0[r * HID + f] * wv;
    }
    #pragma unroll
    for (int r = 0; r < 8; ++r)
        mo[(size_t)(row0 + r) * HID + j] = 1.f / (1.f + expf(-acc[r]));
}

// ---------------- covariance partials: 4 frames staged per sync round ----------------
// part layout: [nc][b][f][72] float2 : slots 0..63 = R[c][d], 64..71 = rhs[c]
__global__ __launch_bounds__(512) void k_cov(const float2* __restrict__ X,
                                             const float* __restrict__ mo,
                                             float2* __restrict__ part) {
    int blk = blockIdx.x;               // ((b*4 + ftile)*8 + nc)
    int nc = blk & 7;
    int ftile = (blk >> 3) & 3;
    int b = blk >> 5;
    int tid = threadIdx.x;
    int c = tid >> 6;
    int ft = tid & 63;
    int f = ftile * 64 + ft;
    int n0 = nc * CCK;
    int n1 = n0 + CCK; if (n1 > NF) n1 = NF;

    __shared__ float2 vbuf[2][NSTG][CH][64];   // 32 KB

    float ar[8], ai[8];
    #pragma unroll
    for (int d = 0; d < 8; ++d) { ar[d] = 0.f; ai[d] = 0.f; }
    float rr = 0.f, ri = 0.f;

    const float2* Xb = X + (size_t)b * NF * CH * FP;
    const float* mb = mo + (size_t)b * NF * HID;

    #pragma unroll
    for (int r = 0; r < NSTG; ++r) {
        int n = n0 + r;
        if (n < n1) vbuf[0][r][c][ft] = Xb[(size_t)(n * CH + c) * FP + f];
    }
    __syncthreads();
    int cur = 0;
    for (int nb = n0; nb < n1; nb += NSTG) {
        int nbn = nb + NSTG;
        float2 nx[NSTG];
        #pragma unroll
        for (int r = 0; r < NSTG; ++r) {
            int n = nbn + r;
            if (n < n1) nx[r] = Xb[(size_t)(n * CH + c) * FP + f];
        }
        float mts[NSTG], mns[NSTG];
        #pragma unroll
        for (int r = 0; r < NSTG; ++r) {
            int n = nb + r;
            if (n < n1) {
                mts[r] = mb[(size_t)n * HID + f];
                mns[r] = mb[(size_t)n * HID + FP + f];
            }
        }
        #pragma unroll
        for (int r = 0; r < NSTG; ++r) {
            int n = nb + r;
            if (n < n1) {
                float mt = mts[r], mn = mns[r];
                float w = mt + mn;
                float2 xc = vbuf[cur][r][c][ft];
                #pragma unroll
                for (int d = 0; d < 8; ++d) {
                    float2 xd = vbuf[cur][r][d][ft];
                    float pr = xc.x * xd.x + xc.y * xd.y;   // xc * conj(xd)
                    float pi = xc.y * xd.x - xc.x * xd.y;
                    ar[d] += w * pr; ai[d] += w * pi;
                    if (d == 0) { rr += mt * pr; ri += mt * pi; }
                }
            }
        }
        if (nbn < n1) {
            #pragma unroll
            for (int r = 0; r < NSTG; ++r) {
                int n = nbn + r;
                if (n < n1) vbuf[cur ^ 1][r][c][ft] = nx[r];
            }
        }
        __syncthreads();
        cur ^= 1;
    }
    float2* pp = part + (((size_t)nc * BATCH + b) * FP + f) * 72;
    #pragma unroll
    for (int d = 0; d < 8; ++d)
        pp[c * 8 + d] = make_float2(ar[d], ai[d]);
    pp[64 + c] = make_float2(rr, ri);
}

// ---------------- reduce partials + 8x8 complex solve: block = (b, fgroup8) ----------------
__global__ __launch_bounds__(512) void k_cov_solve2(const float2* __restrict__ part,
                                                    float2* __restrict__ wc) {
    int blk = blockIdx.x;          // b*32 + fg
    int fg = blk & 31;
    int b = blk >> 5;
    int tid = threadIdx.x;
    int c = tid >> 6, d = (tid >> 3) & 7, fl = tid & 7;
    int f = fg * 8 + fl;
    float ar = 0.f, ai = 0.f, rr = 0.f, ri = 0.f;
    const float2* pb = part + ((size_t)b * FP + f) * 72;
    #pragma unroll
    for (int nc = 0; nc < CNCK; ++nc) {
        const float2* p = pb + (size_t)nc * BATCH * FP * 72;
        float2 v = p[c * 8 + d];
        ar += v.x; ai += v.y;
        if (d == 0) { float2 u = p[64 + c]; rr += u.x; ri += u.y; }
    }
    __shared__ float2 Am[8][73];
    __shared__ float2 rh[8][8];
    __shared__ float2 sl[8][9];
    Am[fl][c * 9 + d] = make_float2(ar, ai);
    if (d == 0) rh[fl][c] = make_float2(rr, ri);
    __syncthreads();
    if (tid < 8) {
        int ln = tid;
        float2* A = Am[ln];
        float2* r = rh[ln];
        float2* sol = sl[ln];
        for (int kk = 0; kk < 8; ++kk) {
            float2 pp = A[kk * 9 + kk];
            float ip = 1.f / (pp.x * pp.x + pp.y * pp.y);
            float invr = pp.x * ip, invi = -pp.y * ip;
            for (int i = kk + 1; i < 8; ++i) {
                float2 aik = A[i * 9 + kk];
                float fr2 = aik.x * invr - aik.y * invi;
                float fi2 = aik.x * invi + aik.y * invr;
                for (int jj = kk; jj < 8; ++jj) {
                    float2 ak = A[kk * 9 + jj];
                    A[i * 9 + jj].x -= fr2 * ak.x - fi2 * ak.y;
                    A[i * 9 + jj].y -= fr2 * ak.y + fi2 * ak.x;
                }
                r[i].x -= fr2 * r[kk].x - fi2 * r[kk].y;
                r[i].y -= fr2 * r[kk].y + fi2 * r[kk].x;
            }
        }
        for (int kk = 7; kk >= 0; --kk) {
            float sr = r[kk].x, si = r[kk].y;
            for (int jj = kk + 1; jj < 8; ++jj) {
                float2 ak = A[kk * 9 + jj];
                float2 xj = sol[jj];
                sr -= ak.x * xj.x - ak.y * xj.y;
                si -= ak.x * xj.y + ak.y * xj.x;
            }
            float2 pp = A[kk * 9 + kk];
            float ip = 1.f / (pp.x * pp.x + pp.y * pp.y);
            sol[kk].x = (sr * pp.x + si * pp.y) * ip;
            sol[kk].y = (si * pp.x - sr * pp.y) * ip;
        }
        for (int cc = 0; cc < 8; ++cc)   // wc layout [b][c][f], store conj
            wc[((size_t)b * CH + cc) * FP + fg * 8 + ln] = make_float2(sol[cc].x, -sol[cc].y);
    }
}

// ---------------- fused beamform + ISTFT: per-frame windowed iDFT rows, no atomics ----------------
__global__ __launch_bounds__(512) void k_istft_bf(const float2* __restrict__ X,
                                                  const float2* __restrict__ wc,
                                                  float* __restrict__ yfr) {
    __shared__ float2 Zp[4 * 512];          // [sig][k] Hermitian-combined spectra
    __shared__ float2 Gl[16 * 32 * 5];      // [k1][tau][sig] pad 5
    int blk = blockIdx.x;
    int g = blk % NGRP, b = blk / NGRP;
    int m0 = g * FPB;
    int tid = threadIdx.x;

    if (tid < 4) Zp[tid * 512] = make_float2(0.f, 0.f);   // k = 0 (DC dropped)
    const float2* Xb0 = X + (size_t)b * NF * CH * FP;
    const float2* wcb = wc + (size_t)b * CH * FP;
    #pragma unroll
    for (int half = 0; half < 2; ++half) {
        int i = half * 512 + tid;
        int sig = i >> 8, kp = i & 255;     // bin kp -> k = kp+1
        int ma = m0 + 2 * sig, mb_ = ma + 1;
        float2 Xa = make_float2(0.f, 0.f), Xb = make_float2(0.f, 0.f);
        if (ma < NF) {
            #pragma unroll
            for (int c = 0; c < 8; ++c) {
                float2 xv = Xb0[(size_t)(ma * CH + c) * FP + kp];
                float2 wv = wcb[c * FP + kp];
                Xa.x += xv.x * wv.x - xv.y * wv.y;
                Xa.y += xv.x * wv.y + xv.y * wv.x;
            }
        }
        if (mb_ < NF) {
            #pragma unroll
            for (int c = 0; c < 8; ++c) {
                float2 xv = Xb0[(size_t)(mb_ * CH + c) * FP + kp];
                float2 wv = wcb[c * FP + kp];
                Xb.x += xv.x * wv.x - xv.y * wv.y;
                Xb.y += xv.x * wv.y + xv.y * wv.x;
            }
        }
        int k = kp + 1;
        if (k == 256) {
            Zp[sig * 512 + 256] = make_float2(Xa.x, Xb.x);   // Nyquist: real parts only
        } else {
            Zp[sig * 512 + k]       = make_float2(Xa.x - Xb.y, Xa.y + Xb.x);
            Zp[sig * 512 + 512 - k] = make_float2(Xa.x + Xb.y, Xb.x - Xa.y);
        }
    }
    __syncthreads();

    // stage 1: G[k1][tau] = sum_{k2} Zp[k1+16*k2] e^{+i 2pi k2 tau/32}
    {
        int k1 = tid >> 5, tau = tid & 31;
        float sa, ca;
        sincosf((float)tau * (float)(2.0 * M_PI / 32.0), &sa, &ca);
        float stepc = ca, steps = sa;
        float gr[4], gi[4];
        #pragma unroll
        for (int s = 0; s < 4; ++s) { gr[s] = 0.f; gi[s] = 0.f; }
        float cr = 1.f, ci = 0.f;
        #pragma unroll 4
        for (int k2 = 0; k2 < 32; ++k2) {
            int k = k1 + 16 * k2;
            #pragma unroll
            for (int s = 0; s < 4; ++s) {
                float2 z = Zp[s * 512 + k];
                gr[s] += z.x * cr - z.y * ci;
                gi[s] += z.x * ci + z.y * cr;
            }
            float ncr = cr * stepc - ci * steps;
            ci = cr * steps + ci * stepc;
            cr = ncr;
        }
        #pragma unroll
        for (int s = 0; s < 4; ++s)
            Gl[(k1 * 32 + tau) * 5 + s] = make_float2(gr[s], gi[s]);
    }
    __syncthreads();

    // stage 2: y_pair[t] = sum_{k1} G[k1][t&31] e^{+i 2pi k1 t/512}; Re->frame a, Im->frame b
    int t = tid;
    int tau = t & 31;
    float sa2, ca2;
    sincosf((float)t * (float)(2.0 * M_PI / 512.0), &sa2, &ca2);
    float stepc = ca2, steps = sa2;
    float accr[4], acci[4];
    #pragma unroll
    for (int s = 0; s < 4; ++s) { accr[s] = 0.f; acci[s] = 0.f; }
    float cr = 1.f, ci = 0.f;
    #pragma unroll 4
    for (int k1 = 0; k1 < 16; ++k1) {
        #pragma unroll
        for (int s = 0; s < 4; ++s) {
            float2 gv = Gl[(k1 * 32 + tau) * 5 + s];
            accr[s] += gv.x * cr - gv.y * ci;
            acci[s] += gv.x * ci + gv.y * cr;
        }
        float ncr = cr * stepc - ci * steps;
        ci = cr * steps + ci * stepc;
        cr = ncr;
    }
    float wv = (0.5f - 0.5f * ca2) * (1.f / 512.f);   // hann(t) / 512
    #pragma unroll
    for (int s = 0; s < 4; ++s) {
        int ma = m0 + 2 * s, mb_ = ma + 1;
        if (ma < NF)  yfr[((size_t)b * NFP + ma) * 512 + t] = accr[s] * wv;
        if (mb_ < NF) yfr[((size_t)b * NFP + mb_) * 512 + t] = acci[s] * wv;
    }
}

// ---------------- gather overlap-add + wsum normalize ----------------
__global__ __launch_bounds__(256) void k_out(const float* __restrict__ yfr,
                                             float* __restrict__ out) {
    int i = blockIdx.x * blockDim.x + threadIdx.x;
    if (i >= BATCH * TLEN) return;
    int b = i / TLEN;
    int t = i - b * TLEN;
    int p = t + PADW;
    int q = p & 127;
    int m0 = p >> 7;
    float sq, cq;
    sincosf((float)q * (float)(2.0 * M_PI / 512.0), &sq, &cq);
    float w4[4] = {0.5f - 0.5f * cq, 0.5f + 0.5f * sq, 0.5f + 0.5f * cq, 0.5f - 0.5f * sq};
    float val = 0.f, wsum = 0.f;
    const float* yb = yfr + (size_t)b * NFP * 512;
    #pragma unroll
    for (int dm = 0; dm < 4; ++dm) {
        int mm = m0 - dm;
        if (mm >= 0 && mm < NF) {
            val += yb[(size_t)mm * 512 + q + 128 * dm];
            wsum += w4[dm] * w4[dm];
        }
    }
    out[i] = val / fmaxf(wsum, 1e-10f);
}

extern "C" void kernel_launch(void* const* d_in, const int* in_sizes, int n_in,
                              void* d_out, int out_size, void* d_ws, size_t ws_size,
                              hipStream_t stream) {
    const float* x  = (const float*)d_in[0];
    const float* w1 = (const float*)d_in[1];
    const float* b1 = (const float*)d_in[2];
    const float* w2 = (const float*)d_in[3];
    const float* b2 = (const float*)d_in[4];

    float* ws = (float*)d_ws;
    size_t off = 0;
    float*  tw   = ws + off; off += 512;
    float2* X    = (float2*)(ws + off); off += (size_t)BATCH * FP * NF * CH * 2;
    float*  feat = ws + off; off += (size_t)BATCH * NF * FP;     // feat+h reused as `part`
    float*  h    = ws + off; off += (size_t)BATCH * NF * HID;
    float*  mo   = ws + off; off += (size_t)BATCH * NF * HID;
    float2* wc   = (float2*)(ws + off); off += (size_t)BATCH * FP * CH * 2;
    float*  yfr  = ws + off; off += (size_t)BATCH * NFP * 512;

    // part: [8][8][256][72] float2 = 9.44 MB <= feat+h (12.3 MB), both dead after mlp2
    float2* part = (float2*)feat;

    k_tables<<<2, 256, 0, stream>>>(tw);
    k_stft<<<BATCH * CH * NGRP, 256, 0, stream>>>(x, tw, X, feat);
    k_mlp1<<<BATCH * NF / 8, 512, 0, stream>>>(feat, w1, b1, h);
    k_mlp2<<<BATCH * NF / 8, 512, 0, stream>>>(h, w2, b2, mo);
    k_cov<<<BATCH * 4 * CNCK, 512, 0, stream>>>(X, mo, part);
    k_cov_solve2<<<BATCH * 32, 512, 0, stream>>>(part, wc);
    k_istft_bf<<<BATCH * NGRP, 512, 0, stream>>>(X, wc, yfr);
    k_out<<<(BATCH * TLEN + 255) / 256, 256, 0, stream>>>(yfr, (float*)d_out);
}

// Round 9
// 155.617 us; speedup vs baseline: 11.3079x; 1.1666x over previous
//
#include <hip/hip_runtime.h>
#include <math.h>

#define NFFT 512
#define HOP  128
#define PADW 256
#define TLEN 64000
#define NF   501
#define NFP  504    // padded frame count for yfr rows
#define FP   256
#define CH   8
#define BATCH 8
#define HID  512
#define MROWS (BATCH * NF)   // 4008
#define FPB  8      // frames per block (stft/istft)
#define NGRP 63     // ceil(NF/FPB)
#define CNCK 8      // cov n-chunks
#define CCK  63     // ceil(NF/CNCK)
#define NSTG 4      // cov frames staged per sync round

#define S2C 0.70710678118654752f

// ---------------- complex helpers ----------------
__device__ __forceinline__ float2 cadd(float2 a, float2 b) { return make_float2(a.x + b.x, a.y + b.y); }
__device__ __forceinline__ float2 csub(float2 a, float2 b) { return make_float2(a.x - b.x, a.y - b.y); }
__device__ __forceinline__ float2 cmul(float2 a, float2 b) { return make_float2(a.x * b.x - a.y * b.y, a.x * b.y + a.y * b.x); }
__device__ __forceinline__ float2 mulnegi(float2 a) { return make_float2(a.y, -a.x); }   // a * (-i)

// forward DFT-8: v[k] = sum_a u[a] * W8^{a k}, W8 = e^{-2pi i/8}
__device__ __forceinline__ void dft8(const float2 u[8], float2 v[8]) {
    float2 a0 = cadd(u[0], u[4]), a1 = cadd(u[1], u[5]), a2 = cadd(u[2], u[6]), a3 = cadd(u[3], u[7]);
    float2 b0 = csub(u[0], u[4]), b1 = csub(u[1], u[5]), b2 = csub(u[2], u[6]), b3 = csub(u[3], u[7]);
    float2 c0 = cadd(a0, a2), c1 = csub(a0, a2), c2 = cadd(a1, a3), c3 = csub(a1, a3);
    v[0] = cadd(c0, c2); v[4] = csub(c0, c2);
    float2 nic3 = mulnegi(c3);
    v[2] = cadd(c1, nic3); v[6] = csub(c1, nic3);
    float2 d1 = make_float2(S2C * (b1.x + b1.y), S2C * (b1.y - b1.x));   // W8^1 * b1
    float2 d2 = mulnegi(b2);                                             // W8^2 * b2
    float2 d3 = make_float2(S2C * (b3.y - b3.x), -S2C * (b3.x + b3.y));  // W8^3 * b3
    float2 e0 = cadd(b0, d2), e1 = csub(b0, d2), e2 = cadd(d1, d3), e3 = csub(d1, d3);
    v[1] = cadd(e0, e2); v[5] = csub(e0, e2);
    float2 nie3 = mulnegi(e3);
    v[3] = cadd(e1, nie3); v[7] = csub(e1, nie3);
}

__device__ __forceinline__ int refl(int j) {
    j = (j < 0) ? -j : j;
    j = (j >= TLEN) ? 2 * (TLEN - 1) - j : j;
    return j;
}

// ---------------- tables: hann window ----------------
__global__ void k_tables(float* tw) {
    int j = threadIdx.x + blockIdx.x * blockDim.x;
    if (j < 512) {
        float ang = (float)(2.0 * M_PI * (double)j / 512.0);
        tw[j] = 0.5f - 0.5f * cosf(ang);
    }
}

// ---------------- STFT: radix-8^3 Stockham FFT on frame-pairs (z = fa + i fb) ----------------
#define A_S 580
#define B_S 544
__global__ __launch_bounds__(256, 4) void k_stft(const float* __restrict__ x,
                                                 const float* __restrict__ tw,
                                                 float2* __restrict__ X,
                                                 float* __restrict__ feat) {
    __shared__ float2 Abuf[4 * A_S];
    __shared__ float2 Bbuf[4 * B_S];
    __shared__ float2 Twd[512];
    int blk = blockIdx.x;
    int g = blk % NGRP;
    int bc = blk / NGRP;
    int c = bc % CH, b = bc / CH;
    int m0 = g * FPB;
    int tid = threadIdx.x;
    const float* xp = x + (size_t)(b * CH + c) * TLEN;

    #pragma unroll
    for (int r = 0; r < 2; ++r) {
        int e = tid + 256 * r;
        float se, ce;
        sincosf((float)e * (float)(2.0 * M_PI / 512.0), &se, &ce);
        Twd[e] = make_float2(ce, -se);
    }

    #pragma unroll
    for (int r = 0; r < 8; ++r) {
        int flat = r * 256 + tid;
        int sig = flat >> 9, t = flat & 511;
        int posa = (m0 + 2 * sig) * HOP + t - PADW;
        float xa = xp[refl(posa)];
        float xb = xp[refl(posa + HOP)];
        float w = tw[t];
        Abuf[sig * A_S + t] = make_float2(xa * w, xb * w);
    }
    __syncthreads();

    int sig = tid >> 6, dft = tid & 63;
    float2 u[8], v[8];

    // stage 1
    {
        const float2* Az = &Abuf[sig * A_S];
        float2* Bu = &Bbuf[sig * B_S];
        #pragma unroll
        for (int a = 0; a < 8; ++a) u[a] = Az[64 * a + dft];
        dft8(u, v);
        #pragma unroll
        for (int k0 = 0; k0 < 8; ++k0) Bu[k0 * 68 + dft] = v[k0];
    }
    __syncthreads();

    // stage 2
    {
        int k0 = dft >> 3, cd = dft & 7;
        const float2* Bu = &Bbuf[sig * B_S];
        float2* Au = &Abuf[sig * A_S];
        #pragma unroll
        for (int bb = 0; bb < 8; ++bb) u[bb] = Bu[k0 * 68 + 8 * bb + cd];
        #pragma unroll
        for (int bb = 1; bb < 8; ++bb) u[bb] = cmul(u[bb], Twd[(8 * bb * k0) & 511]);
        dft8(u, v);
        #pragma unroll
        for (int k1 = 0; k1 < 8; ++k1) Au[(8 * k0 + k1) * 9 + cd] = v[k1];
    }
    __syncthreads();

    // stage 3
    {
        int k0 = dft >> 3, k1 = dft & 7;
        int kk = k0 + 8 * k1;
        const float2* Au = &Abuf[sig * A_S];
        float2* Bz = &Bbuf[sig * B_S];
        #pragma unroll
        for (int cd = 0; cd < 8; ++cd) u[cd] = Au[dft * 9 + cd];
        #pragma unroll
        for (int cd = 1; cd < 8; ++cd) u[cd] = cmul(u[cd], Twd[(cd * kk) & 511]);
        dft8(u, v);
        #pragma unroll
        for (int k2 = 0; k2 < 8; ++k2) Bz[kk + 64 * k2] = v[k2];
    }
    __syncthreads();

    // Hermitian unpack
    {
        int kp = tid;
        int k = kp + 1;
        #pragma unroll
        for (int s = 0; s < 4; ++s) {
            float2 z1 = Bbuf[s * B_S + k];
            float2 z2 = Bbuf[s * B_S + (512 - k)];
            float Ar = 0.5f * (z1.x + z2.x);
            float Ai = 0.5f * (z1.y - z2.y);
            float Br = 0.5f * (z1.y + z2.y);
            float Bi = 0.5f * (z2.x - z1.x);
            int ma = m0 + 2 * s, mb_ = ma + 1;
            if (ma < NF) {
                X[((size_t)(b * NF + ma) * CH + c) * FP + kp] = make_float2(Ar, Ai);
                if (c == 0) feat[((size_t)b * NF + ma) * FP + kp] = sqrtf(Ar * Ar + Ai * Ai);
            }
            if (mb_ < NF) {
                X[((size_t)(b * NF + mb_) * CH + c) * FP + kp] = make_float2(Br, Bi);
                if (c == 0) feat[((size_t)b * NF + mb_) * FP + kp] = sqrtf(Br * Br + Bi * Bi);
            }
        }
    }
}

// ---------------- MLP as tiled fp32 GEMM: out[M][512] = act(A[M][K] @ W[K][512] + bias) ----------------
// 64x64 block tile, 4x4 microtile, K staged 32 at a time. ACT: 0 = relu, 1 = sigmoid.
template<int K, int ACT>
__global__ __launch_bounds__(256) void k_gemm(const float* __restrict__ A,
                                              const float* __restrict__ W,
                                              const float* __restrict__ bias,
                                              float* __restrict__ out, int M) {
    __shared__ float As[64][36];   // [row][k] pad 36 (144B rows, 16B aligned)
    __shared__ float Bs[32][68];   // [k][col] pad 68 (272B rows, 16B aligned)
    int m0 = (blockIdx.x >> 3) << 6;
    int n0 = (blockIdx.x & 7) << 6;
    int tid = threadIdx.x;
    int tm = tid >> 4, tn = tid & 15;

    float4 bj = *(const float4*)&bias[n0 + tn * 4];
    float4 acc[4];
    #pragma unroll
    for (int r = 0; r < 4; ++r) acc[r] = bj;

    int lrowA = tid >> 3;            // 0..31 (and +32)
    int lkA   = (tid & 7) * 4;       // 0,4,..28
    int lkB   = tid >> 4;            // 0..15 (and +16)
    int lnB   = (tid & 15) * 4;

    int ra = m0 + lrowA;  if (ra > M - 1) ra = M - 1;
    int rb = m0 + lrowA + 32; if (rb > M - 1) rb = M - 1;

    for (int kt = 0; kt < K; kt += 32) {
        float4 a0 = *(const float4*)&A[(size_t)ra * K + kt + lkA];
        float4 a1 = *(const float4*)&A[(size_t)rb * K + kt + lkA];
        float4 b0 = *(const float4*)&W[(size_t)(kt + lkB) * HID + n0 + lnB];
        float4 b1 = *(const float4*)&W[(size_t)(kt + lkB + 16) * HID + n0 + lnB];
        if (kt > 0) __syncthreads();
        *(float4*)&As[lrowA][lkA] = a0;
        *(float4*)&As[lrowA + 32][lkA] = a1;
        *(float4*)&Bs[lkB][lnB] = b0;
        *(float4*)&Bs[lkB + 16][lnB] = b1;
        __syncthreads();
        #pragma unroll
        for (int k4 = 0; k4 < 8; ++k4) {
            float4 av[4], bq[4];
            #pragma unroll
            for (int r = 0; r < 4; ++r) av[r] = *(const float4*)&As[tm * 4 + r][k4 * 4];
            #pragma unroll
            for (int e = 0; e < 4; ++e) bq[e] = *(const float4*)&Bs[k4 * 4 + e][tn * 4];
            #pragma unroll
            for (int e = 0; e < 4; ++e) {
                #pragma unroll
                for (int r = 0; r < 4; ++r) {
                    float ae = ((const float*)&av[r])[e];
                    acc[r].x += ae * bq[e].x;
                    acc[r].y += ae * bq[e].y;
                    acc[r].z += ae * bq[e].z;
                    acc[r].w += ae * bq[e].w;
                }
            }
        }
    }

    #pragma unroll
    for (int r = 0; r < 4; ++r) {
        int m = m0 + tm * 4 + r;
        if (m < M) {
            float4 v = acc[r];
            if (ACT == 0) {
                v.x = fmaxf(v.x, 0.f); v.y = fmaxf(v.y, 0.f);
                v.z = fmaxf(v.z, 0.f); v.w = fmaxf(v.w, 0.f);
            } else {
                v.x = 1.f / (1.f + expf(-v.x)); v.y = 1.f / (1.f + expf(-v.y));
                v.z = 1.f / (1.f + expf(-v.z)); v.w = 1.f / (1.f + expf(-v.w));
            }
            *(float4*)&out[(size_t)m * HID + n0 + tn * 4] = v;
        }
    }
}

// ---------------- covariance partials: 4 frames staged per sync round ----------------
// part layout: [nc][b][f][72] float2 : slots 0..63 = R[c][d], 64..71 = rhs[c]
__global__ __launch_bounds__(512) void k_cov(const float2* __restrict__ X,
                                             const float* __restrict__ mo,
                                             float2* __restrict__ part) {
    int blk = blockIdx.x;               // ((b*4 + ftile)*8 + nc)
    int nc = blk & 7;
    int ftile = (blk >> 3) & 3;
    int b = blk >> 5;
    int tid = threadIdx.x;
    int c = tid >> 6;
    int ft = tid & 63;
    int f = ftile * 64 + ft;
    int n0 = nc * CCK;
    int n1 = n0 + CCK; if (n1 > NF) n1 = NF;

    __shared__ float2 vbuf[2][NSTG][CH][64];   // 32 KB

    float ar[8], ai[8];
    #pragma unroll
    for (int d = 0; d < 8; ++d) { ar[d] = 0.f; ai[d] = 0.f; }
    float rr = 0.f, ri = 0.f;

    const float2* Xb = X + (size_t)b * NF * CH * FP;
    const float* mb = mo + (size_t)b * NF * HID;

    #pragma unroll
    for (int r = 0; r < NSTG; ++r) {
        int n = n0 + r;
        if (n < n1) vbuf[0][r][c][ft] = Xb[(size_t)(n * CH + c) * FP + f];
    }
    __syncthreads();
    int cur = 0;
    for (int nb = n0; nb < n1; nb += NSTG) {
        int nbn = nb + NSTG;
        float2 nx[NSTG];
        #pragma unroll
        for (int r = 0; r < NSTG; ++r) {
            int n = nbn + r;
            if (n < n1) nx[r] = Xb[(size_t)(n * CH + c) * FP + f];
        }
        float mts[NSTG], mns[NSTG];
        #pragma unroll
        for (int r = 0; r < NSTG; ++r) {
            int n = nb + r;
            if (n < n1) {
                mts[r] = mb[(size_t)n * HID + f];
                mns[r] = mb[(size_t)n * HID + FP + f];
            }
        }
        #pragma unroll
        for (int r = 0; r < NSTG; ++r) {
            int n = nb + r;
            if (n < n1) {
                float mt = mts[r], mn = mns[r];
                float w = mt + mn;
                float2 xc = vbuf[cur][r][c][ft];
                #pragma unroll
                for (int d = 0; d < 8; ++d) {
                    float2 xd = vbuf[cur][r][d][ft];
                    float pr = xc.x * xd.x + xc.y * xd.y;   // xc * conj(xd)
                    float pi = xc.y * xd.x - xc.x * xd.y;
                    ar[d] += w * pr; ai[d] += w * pi;
                    if (d == 0) { rr += mt * pr; ri += mt * pi; }
                }
            }
        }
        if (nbn < n1) {
            #pragma unroll
            for (int r = 0; r < NSTG; ++r) {
                int n = nbn + r;
                if (n < n1) vbuf[cur ^ 1][r][c][ft] = nx[r];
            }
        }
        __syncthreads();
        cur ^= 1;
    }
    float2* pp = part + (((size_t)nc * BATCH + b) * FP + f) * 72;
    #pragma unroll
    for (int d = 0; d < 8; ++d)
        pp[c * 8 + d] = make_float2(ar[d], ai[d]);
    pp[64 + c] = make_float2(rr, ri);
}

// ---------------- reduce partials + 8x8 complex solve: block = (b, fgroup8) ----------------
__global__ __launch_bounds__(512) void k_cov_solve2(const float2* __restrict__ part,
                                                    float2* __restrict__ wc) {
    int blk = blockIdx.x;          // b*32 + fg
    int fg = blk & 31;
    int b = blk >> 5;
    int tid = threadIdx.x;
    int c = tid >> 6, d = (tid >> 3) & 7, fl = tid & 7;
    int f = fg * 8 + fl;
    float ar = 0.f, ai = 0.f, rr = 0.f, ri = 0.f;
    const float2* pb = part + ((size_t)b * FP + f) * 72;
    #pragma unroll
    for (int nc = 0; nc < CNCK; ++nc) {
        const float2* p = pb + (size_t)nc * BATCH * FP * 72;
        float2 v = p[c * 8 + d];
        ar += v.x; ai += v.y;
        if (d == 0) { float2 u = p[64 + c]; rr += u.x; ri += u.y; }
    }
    __shared__ float2 Am[8][73];
    __shared__ float2 rh[8][8];
    __shared__ float2 sl[8][9];
    Am[fl][c * 9 + d] = make_float2(ar, ai);
    if (d == 0) rh[fl][c] = make_float2(rr, ri);
    __syncthreads();
    if (tid < 8) {
        int ln = tid;
        float2* A = Am[ln];
        float2* r = rh[ln];
        float2* sol = sl[ln];
        for (int kk = 0; kk < 8; ++kk) {
            float2 pp = A[kk * 9 + kk];
            float ip = 1.f / (pp.x * pp.x + pp.y * pp.y);
            float invr = pp.x * ip, invi = -pp.y * ip;
            for (int i = kk + 1; i < 8; ++i) {
                float2 aik = A[i * 9 + kk];
                float fr2 = aik.x * invr - aik.y * invi;
                float fi2 = aik.x * invi + aik.y * invr;
                for (int jj = kk; jj < 8; ++jj) {
                    float2 ak = A[kk * 9 + jj];
                    A[i * 9 + jj].x -= fr2 * ak.x - fi2 * ak.y;
                    A[i * 9 + jj].y -= fr2 * ak.y + fi2 * ak.x;
                }
                r[i].x -= fr2 * r[kk].x - fi2 * r[kk].y;
                r[i].y -= fr2 * r[kk].y + fi2 * r[kk].x;
            }
        }
        for (int kk = 7; kk >= 0; --kk) {
            float sr = r[kk].x, si = r[kk].y;
            for (int jj = kk + 1; jj < 8; ++jj) {
                float2 ak = A[kk * 9 + jj];
                float2 xj = sol[jj];
                sr -= ak.x * xj.x - ak.y * xj.y;
                si -= ak.x * xj.y + ak.y * xj.x;
            }
            float2 pp = A[kk * 9 + kk];
            float ip = 1.f / (pp.x * pp.x + pp.y * pp.y);
            sol[kk].x = (sr * pp.x + si * pp.y) * ip;
            sol[kk].y = (si * pp.x - sr * pp.y) * ip;
        }
        for (int cc = 0; cc < 8; ++cc)   // wc layout [b][c][f], store conj
            wc[((size_t)b * CH + cc) * FP + fg * 8 + ln] = make_float2(sol[cc].x, -sol[cc].y);
    }
}

// ---------------- fused beamform + ISTFT: per-frame windowed iDFT rows, no atomics ----------------
__global__ __launch_bounds__(512) void k_istft_bf(const float2* __restrict__ X,
                                                  const float2* __restrict__ wc,
                                                  float* __restrict__ yfr) {
    __shared__ float2 Zp[4 * 512];          // [sig][k] Hermitian-combined spectra
    __shared__ float2 Gl[16 * 32 * 5];      // [k1][tau][sig] pad 5
    int blk = blockIdx.x;
    int g = blk % NGRP, b = blk / NGRP;
    int m0 = g * FPB;
    int tid = threadIdx.x;

    if (tid < 4) Zp[tid * 512] = make_float2(0.f, 0.f);   // k = 0 (DC dropped)
    const float2* Xb0 = X + (size_t)b * NF * CH * FP;
    const float2* wcb = wc + (size_t)b * CH * FP;
    #pragma unroll
    for (int half = 0; half < 2; ++half) {
        int i = half * 512 + tid;
        int sig = i >> 8, kp = i & 255;     // bin kp -> k = kp+1
        int ma = m0 + 2 * sig, mb_ = ma + 1;
        float2 Xa = make_float2(0.f, 0.f), Xb = make_float2(0.f, 0.f);
        if (ma < NF) {
            #pragma unroll
            for (int c = 0; c < 8; ++c) {
                float2 xv = Xb0[(size_t)(ma * CH + c) * FP + kp];
                float2 wv = wcb[c * FP + kp];
                Xa.x += xv.x * wv.x - xv.y * wv.y;
                Xa.y += xv.x * wv.y + xv.y * wv.x;
            }
        }
        if (mb_ < NF) {
            #pragma unroll
            for (int c = 0; c < 8; ++c) {
                float2 xv = Xb0[(size_t)(mb_ * CH + c) * FP + kp];
                float2 wv = wcb[c * FP + kp];
                Xb.x += xv.x * wv.x - xv.y * wv.y;
                Xb.y += xv.x * wv.y + xv.y * wv.x;
            }
        }
        int k = kp + 1;
        if (k == 256) {
            Zp[sig * 512 + 256] = make_float2(Xa.x, Xb.x);   // Nyquist: real parts only
        } else {
            Zp[sig * 512 + k]       = make_float2(Xa.x - Xb.y, Xa.y + Xb.x);
            Zp[sig * 512 + 512 - k] = make_float2(Xa.x + Xb.y, Xb.x - Xa.y);
        }
    }
    __syncthreads();

    // stage 1: G[k1][tau] = sum_{k2} Zp[k1+16*k2] e^{+i 2pi k2 tau/32}
    {
        int k1 = tid >> 5, tau = tid & 31;
        float sa, ca;
        sincosf((float)tau * (float)(2.0 * M_PI / 32.0), &sa, &ca);
        float stepc = ca, steps = sa;
        float gr[4], gi[4];
        #pragma unroll
        for (int s = 0; s < 4; ++s) { gr[s] = 0.f; gi[s] = 0.f; }
        float cr = 1.f, ci = 0.f;
        #pragma unroll 4
        for (int k2 = 0; k2 < 32; ++k2) {
            int k = k1 + 16 * k2;
            #pragma unroll
            for (int s = 0; s < 4; ++s) {
                float2 z = Zp[s * 512 + k];
                gr[s] += z.x * cr - z.y * ci;
                gi[s] += z.x * ci + z.y * cr;
            }
            float ncr = cr * stepc - ci * steps;
            ci = cr * steps + ci * stepc;
            cr = ncr;
        }
        #pragma unroll
        for (int s = 0; s < 4; ++s)
            Gl[(k1 * 32 + tau) * 5 + s] = make_float2(gr[s], gi[s]);
    }
    __syncthreads();

    // stage 2: y_pair[t] = sum_{k1} G[k1][t&31] e^{+i 2pi k1 t/512}; Re->frame a, Im->frame b
    int t = tid;
    int tau = t & 31;
    float sa2, ca2;
    sincosf((float)t * (float)(2.0 * M_PI / 512.0), &sa2, &ca2);
    float stepc = ca2, steps = sa2;
    float accr[4], acci[4];
    #pragma unroll
    for (int s = 0; s < 4; ++s) { accr[s] = 0.f; acci[s] = 0.f; }
    float cr = 1.f, ci = 0.f;
    #pragma unroll 4
    for (int k1 = 0; k1 < 16; ++k1) {
        #pragma unroll
        for (int s = 0; s < 4; ++s) {
            float2 gv = Gl[(k1 * 32 + tau) * 5 + s];
            accr[s] += gv.x * cr - gv.y * ci;
            acci[s] += gv.x * ci + gv.y * cr;
        }
        float ncr = cr * stepc - ci * steps;
        ci = cr * steps + ci * stepc;
        cr = ncr;
    }
    float wv = (0.5f - 0.5f * ca2) * (1.f / 512.f);   // hann(t) / 512
    #pragma unroll
    for (int s = 0; s < 4; ++s) {
        int ma = m0 + 2 * s, mb_ = ma + 1;
        if (ma < NF)  yfr[((size_t)b * NFP + ma) * 512 + t] = accr[s] * wv;
        if (mb_ < NF) yfr[((size_t)b * NFP + mb_) * 512 + t] = acci[s] * wv;
    }
}

// ---------------- gather overlap-add + wsum normalize ----------------
__global__ __launch_bounds__(256) void k_out(const float* __restrict__ yfr,
                                             float* __restrict__ out) {
    int i = blockIdx.x * blockDim.x + threadIdx.x;
    if (i >= BATCH * TLEN) return;
    int b = i / TLEN;
    int t = i - b * TLEN;
    int p = t + PADW;
    int q = p & 127;
    int m0 = p >> 7;
    float sq, cq;
    sincosf((float)q * (float)(2.0 * M_PI / 512.0), &sq, &cq);
    float w4[4] = {0.5f - 0.5f * cq, 0.5f + 0.5f * sq, 0.5f + 0.5f * cq, 0.5f - 0.5f * sq};
    float val = 0.f, wsum = 0.f;
    const float* yb = yfr + (size_t)b * NFP * 512;
    #pragma unroll
    for (int dm = 0; dm < 4; ++dm) {
        int mm = m0 - dm;
        if (mm >= 0 && mm < NF) {
            val += yb[(size_t)mm * 512 + q + 128 * dm];
            wsum += w4[dm] * w4[dm];
        }
    }
    out[i] = val / fmaxf(wsum, 1e-10f);
}

extern "C" void kernel_launch(void* const* d_in, const int* in_sizes, int n_in,
                              void* d_out, int out_size, void* d_ws, size_t ws_size,
                              hipStream_t stream) {
    const float* x  = (const float*)d_in[0];
    const float* w1 = (const float*)d_in[1];
    const float* b1 = (const float*)d_in[2];
    const float* w2 = (const float*)d_in[3];
    const float* b2 = (const float*)d_in[4];

    float* ws = (float*)d_ws;
    size_t off = 0;
    float*  tw   = ws + off; off += 512;
    float2* X    = (float2*)(ws + off); off += (size_t)BATCH * FP * NF * CH * 2;
    float*  feat = ws + off; off += (size_t)BATCH * NF * FP;     // feat+h reused as `part`
    float*  h    = ws + off; off += (size_t)BATCH * NF * HID;
    float*  mo   = ws + off; off += (size_t)BATCH * NF * HID;
    float2* wc   = (float2*)(ws + off); off += (size_t)BATCH * FP * CH * 2;
    float*  yfr  = ws + off; off += (size_t)BATCH * NFP * 512;

    // part: [8][8][256][72] float2 = 9.44 MB <= feat+h (12.3 MB), both dead after mlp2
    float2* part = (float2*)feat;

    k_tables<<<2, 256, 0, stream>>>(tw);
    k_stft<<<BATCH * CH * NGRP, 256, 0, stream>>>(x, tw, X, feat);
    k_gemm<256, 0><<<63 * 8, 256, 0, stream>>>(feat, w1, b1, h, MROWS);
    k_gemm<512, 1><<<63 * 8, 256, 0, stream>>>(h, w2, b2, mo, MROWS);
    k_cov<<<BATCH * 4 * CNCK, 512, 0, stream>>>(X, mo, part);
    k_cov_solve2<<<BATCH * 32, 512, 0, stream>>>(part, wc);
    k_istft_bf<<<BATCH * NGRP, 512, 0, stream>>>(X, wc, yfr);
    k_out<<<(BATCH * TLEN + 255) / 256, 256, 0, stream>>>(yfr, (float*)d_out);
}